// Round 2
// baseline (7702.227 us; speedup 1.0000x reference)
//
#include <hip/hip_runtime.h>
#include <hip/hip_bf16.h>

// Problem constants
#define BDIM 4
#define KDIM 1024
#define LDIM 32
#define DDIM 128
#define HDIM 8
#define DFFC 512
#define EDIM 16384
#define NSEQ (BDIM * KDIM)   // 4096

typedef unsigned short ushort_t;
typedef unsigned int   uint32;

__device__ __forceinline__ float bf2f(uint32 u) {
    union { uint32 i; float f; } v; v.i = u << 16; return v.f;
}
__device__ __forceinline__ ushort_t f2bf(float f) {
    union { float f; uint32 i; } v; v.f = f;
    uint32 r = (v.i + 0x7fffu + ((v.i >> 16) & 1u)) >> 16;
    return (ushort_t)r;
}
__device__ __forceinline__ void unpack8(uint4 v, float* dst) {
    const uint32* pv = (const uint32*)&v;
#pragma unroll
    for (int q = 0; q < 4; q++) {
        uint32 w = pv[q];
        dst[2 * q]     = bf2f(w & 0xffffu);
        dst[2 * q + 1] = bf2f(w >> 16);
    }
}

// dot of 16 fp32 h-values with 16 fp32 weights (4 x float4)
__device__ __forceinline__ float dot16f(const float* h, const float* w) {
    const float4* pw = (const float4*)w;
    float s = 0.f;
#pragma unroll
    for (int q = 0; q < 4; q++) {
        float4 v = pw[q];
        s += h[4 * q + 0] * v.x + h[4 * q + 1] * v.y
           + h[4 * q + 2] * v.z + h[4 * q + 3] * v.w;
    }
    return s;
}

// For one 8-wide chunk of output columns [jc, jc+8): each of the 8 lanes
// (same row l, tsub=0..7) computes 16-element partials for all 8 columns,
// butterfly-reduces over the 8-lane group, and keeps column jc+tsub.
__device__ __forceinline__ float gemm_chunk(const float* h, const float* wbase,
                                            int jc, int ds, int tsub) {
    float p[8];
#pragma unroll
    for (int jj = 0; jj < 8; jj++)
        p[jj] = dot16f(h, wbase + (size_t)(jc + jj) * DDIM + ds);
#pragma unroll
    for (int m = 1; m < 8; m <<= 1) {
#pragma unroll
        for (int jj = 0; jj < 8; jj++) p[jj] += __shfl_xor(p[jj], m);
    }
    float myv = 0.f;
#pragma unroll
    for (int jj = 0; jj < 8; jj++) if (tsub == jj) myv = p[jj];
    return myv;
}

// ---------------------------------------------------------------------------
// Fused transformer encoder layer per sequence tile [32,128] + gcn_w GEMM.
// Block = 256 threads, grid = 4096 (one per (b,k) node).
// LDS regions (aliased by phase, barriers between):
//   regionA [0, 33280):  qkv bf16 [32][392]  ->  u fp32 [32][129]  ->  f1 bf16 [32][520]
//   regionB [33280, 49792):  o fp32 [32][129] -> f2 fp32 [32][129]
// ---------------------------------------------------------------------------
__global__ __launch_bounds__(256)
void k_transformer(const float* __restrict__ x,
                   const float* __restrict__ w_qkv, const float* __restrict__ b_qkv,
                   const float* __restrict__ w_out, const float* __restrict__ b_out,
                   const float* __restrict__ w1, const float* __restrict__ b1,
                   const float* __restrict__ w2, const float* __restrict__ b2,
                   const float* __restrict__ ln1g, const float* __restrict__ ln1b,
                   const float* __restrict__ ln2g, const float* __restrict__ ln2b,
                   const float* __restrict__ gcnw,
                   float* __restrict__ out_xt,
                   ushort_t* __restrict__ hh)
{
    const int n    = blockIdx.x;
    const int tid  = threadIdx.x;
    const int l    = tid >> 3;
    const int tsub = tid & 7;
    const int ds   = tsub * 16;

    __shared__ __align__(16) char smem[49792];
    ushort_t* s_qkv = (ushort_t*)smem;              // [32][392] bf16
    float*    s_u   = (float*)smem;                 // [32][129] fp32 (aliases qkv)
    ushort_t* s_f1  = (ushort_t*)smem;              // [32][520] bf16 (aliases qkv/u)
    float*    s_o   = (float*)(smem + 33280);       // [32][129] fp32

    // ---- load h0 (own 16 elements of the tile) ----
    float h0[16];
    {
        const float4* px = (const float4*)(x + (size_t)n * 4096 + tid * 16);
#pragma unroll
        for (int q = 0; q < 4; q++) {
            float4 v = px[q];
            h0[4 * q] = v.x; h0[4 * q + 1] = v.y; h0[4 * q + 2] = v.z; h0[4 * q + 3] = v.w;
        }
    }

    // ---- Phase 1: QKV = h0 @ w_qkv^T + b_qkv  -> s_qkv bf16 ----
#pragma unroll 1
    for (int jc = 0; jc < 384; jc += 8) {
        float myv = gemm_chunk(h0, w_qkv, jc, ds, tsub) + b_qkv[jc + tsub];
        s_qkv[l * 392 + jc + tsub] = f2bf(myv);
    }
    __syncthreads();

    // ---- Phase 2: attention (head = tid>>5, lq = tid&31) ----
    {
        const int head = tid >> 5;
        const int lq   = tid & 31;
        const ushort_t* qrow = s_qkv + lq * 392 + head * 16;
        float q[16];
#pragma unroll
        for (int t = 0; t < 16; t++) q[t] = bf2f((uint32)qrow[t]);
        float sc[32];
        float mx = -1e30f;
#pragma unroll
        for (int m = 0; m < 32; m++) {
            const ushort_t* krow = s_qkv + m * 392 + 128 + head * 16;
            float s = 0.f;
#pragma unroll
            for (int t = 0; t < 16; t++) s += q[t] * bf2f((uint32)krow[t]);
            s *= 0.25f;                 // 1/sqrt(dh), dh=16
            sc[m] = s;
            mx = fmaxf(mx, s);
        }
        float sum = 0.f;
#pragma unroll
        for (int m = 0; m < 32; m++) { float e = __expf(sc[m] - mx); sc[m] = e; sum += e; }
        float inv = 1.f / sum;
        float o[16];
#pragma unroll
        for (int t = 0; t < 16; t++) o[t] = 0.f;
#pragma unroll
        for (int m = 0; m < 32; m++) {
            const ushort_t* vrow = s_qkv + m * 392 + 256 + head * 16;
            float a = sc[m];
#pragma unroll
            for (int t = 0; t < 16; t++) o[t] += a * bf2f((uint32)vrow[t]);
        }
#pragma unroll
        for (int t = 0; t < 16; t++) s_o[lq * 129 + head * 16 + t] = o[t] * inv;
    }
    __syncthreads();   // all qkv reads done; s_o complete

    // ---- Phase 3: u = o @ w_out^T + b_out -> s_u (aliases qkv region) ----
    {
        float ov[16];
#pragma unroll
        for (int i = 0; i < 16; i++) ov[i] = s_o[l * 129 + ds + i];
#pragma unroll 1
        for (int jc = 0; jc < 128; jc += 8) {
            float myv = gemm_chunk(ov, w_out, jc, ds, tsub) + b_out[jc + tsub];
            s_u[l * 129 + jc + tsub] = myv;
        }
    }
    __syncthreads();

    // ---- LN1: h1 = LN(h0 + u) ----
    float h1[16];
    {
        float t[16]; float sum = 0.f;
#pragma unroll
        for (int i = 0; i < 16; i++) { t[i] = h0[i] + s_u[l * 129 + ds + i]; sum += t[i]; }
        sum += __shfl_xor(sum, 1); sum += __shfl_xor(sum, 2); sum += __shfl_xor(sum, 4);
        float mean = sum * (1.f / 128.f);
        float vs = 0.f;
#pragma unroll
        for (int i = 0; i < 16; i++) { float d = t[i] - mean; vs += d * d; }
        vs += __shfl_xor(vs, 1); vs += __shfl_xor(vs, 2); vs += __shfl_xor(vs, 4);
        float rs = rsqrtf(vs * (1.f / 128.f) + 1e-5f);
#pragma unroll
        for (int i = 0; i < 16; i++)
            h1[i] = (t[i] - mean) * rs * ln1g[ds + i] + ln1b[ds + i];
    }
    __syncthreads();   // before f1 overwrites regionA

    // ---- FFN1: f1 = relu(h1 @ w1^T + b1) -> s_f1 bf16 [32][520] ----
#pragma unroll 1
    for (int jc = 0; jc < DFFC; jc += 8) {
        float myv = gemm_chunk(h1, w1, jc, ds, tsub) + b1[jc + tsub];
        s_f1[l * 520 + jc + tsub] = f2bf(fmaxf(myv, 0.f));
    }
    __syncthreads();

    // ---- FFN2: f2 = f1 @ w2^T + b2 -> s_o (f2, fp32) ----
    {
        float f[64];   // own contiguous 64 of the 512 (cols [tsub*64, tsub*64+64))
        const uint4* pf = (const uint4*)(s_f1 + l * 520 + tsub * 64);
#pragma unroll
        for (int q = 0; q < 8; q++) { uint4 v = pf[q]; unpack8(v, &f[8 * q]); }
#pragma unroll 1
        for (int jc = 0; jc < 128; jc += 8) {
            float p[8];
#pragma unroll
            for (int jj = 0; jj < 8; jj++) {
                const float4* pw = (const float4*)(w2 + (size_t)(jc + jj) * DFFC + tsub * 64);
                float s = 0.f;
#pragma unroll
                for (int q = 0; q < 16; q++) {
                    float4 wv = pw[q];
                    s += f[4 * q] * wv.x + f[4 * q + 1] * wv.y
                       + f[4 * q + 2] * wv.z + f[4 * q + 3] * wv.w;
                }
                p[jj] = s;
            }
#pragma unroll
            for (int m = 1; m < 8; m <<= 1) {
#pragma unroll
                for (int jj = 0; jj < 8; jj++) p[jj] += __shfl_xor(p[jj], m);
            }
            float myv = 0.f;
#pragma unroll
            for (int jj = 0; jj < 8; jj++) if (tsub == jj) myv = p[jj];
            s_o[l * 129 + jc + tsub] = myv + b2[jc + tsub];
        }
    }
    __syncthreads();

    // ---- LN2: h2 = LN(h1 + f2) ----
    float h2[16];
    {
        float t[16]; float sum = 0.f;
#pragma unroll
        for (int i = 0; i < 16; i++) { t[i] = h1[i] + s_o[l * 129 + ds + i]; sum += t[i]; }
        sum += __shfl_xor(sum, 1); sum += __shfl_xor(sum, 2); sum += __shfl_xor(sum, 4);
        float mean = sum * (1.f / 128.f);
        float vs = 0.f;
#pragma unroll
        for (int i = 0; i < 16; i++) { float d = t[i] - mean; vs += d * d; }
        vs += __shfl_xor(vs, 1); vs += __shfl_xor(vs, 2); vs += __shfl_xor(vs, 4);
        float rs = rsqrtf(vs * (1.f / 128.f) + 1e-5f);
#pragma unroll
        for (int i = 0; i < 16; i++)
            h2[i] = (t[i] - mean) * rs * ln2g[ds + i] + ln2b[ds + i];
    }

    // ---- write xt (d_out, fp32) ----
    {
        float4* po = (float4*)(out_xt + (size_t)n * 4096 + tid * 16);
#pragma unroll
        for (int q = 0; q < 4; q++)
            po[q] = make_float4(h2[4 * q], h2[4 * q + 1], h2[4 * q + 2], h2[4 * q + 3]);
    }

    // ---- hh = h2 @ gcn_w^T (no bias) -> ws (bf16) ----
#pragma unroll 1
    for (int jc = 0; jc < 128; jc += 8) {
        float myv = gemm_chunk(h2, gcnw, jc, ds, tsub);
        hh[(size_t)n * 4096 + l * 128 + jc + tsub] = f2bf(myv);
    }
}

// ---------------------------------------------------------------------------
// GCN support kernels
// ---------------------------------------------------------------------------
__global__ void k_init(float* deg, int* count) {
    int i = blockIdx.x * 256 + threadIdx.x;
    if (i < BDIM * KDIM) { deg[i] = 1.0f; count[i] = 0; }   // 1.0 = self loop weight
}

__global__ void k_degcount(const int* __restrict__ ei, const float* __restrict__ ew,
                           float* deg, int* count) {
    int idx = blockIdx.x * 256 + threadIdx.x;
    if (idx >= BDIM * EDIM) return;
    int b = idx / EDIM, e = idx - b * EDIM;
    int col = ei[(size_t)b * 2 * EDIM + EDIM + e];
    float w = ew[(size_t)b * EDIM + e];
    atomicAdd(&deg[b * KDIM + col], w);
    atomicAdd(&count[b * KDIM + col], 1);
}

__global__ __launch_bounds__(1024)
void k_scan(const int* __restrict__ count, int* offs, int* cursor) {
    __shared__ int s[KDIM];
    int b = blockIdx.x, i = threadIdx.x;
    int c = count[b * KDIM + i];
    s[i] = c; __syncthreads();
#pragma unroll 1
    for (int off = 1; off < KDIM; off <<= 1) {
        int t = (i >= off) ? s[i - off] : 0;
        __syncthreads();
        s[i] += t;
        __syncthreads();
    }
    int excl = s[i] - c;
    offs[b * KDIM + i] = excl;
    cursor[b * KDIM + i] = excl;
}

__global__ void k_fill(const int* __restrict__ ei, int* cursor, int* elist) {
    int idx = blockIdx.x * 256 + threadIdx.x;
    if (idx >= BDIM * EDIM) return;
    int b = idx / EDIM, e = idx - b * EDIM;
    int col = ei[(size_t)b * 2 * EDIM + EDIM + e];
    int pos = atomicAdd(&cursor[b * KDIM + col], 1);
    elist[(size_t)b * EDIM + pos] = e;
}

// One block per node (b,i): out = xt + segment_sum(msg) + gcn_b
__global__ __launch_bounds__(256)
void k_gather(const int* __restrict__ ei, const float* __restrict__ ew,
              const float* __restrict__ deg, const int* __restrict__ offs,
              const int* __restrict__ count, const int* __restrict__ elist,
              const ushort_t* __restrict__ hh, const float* __restrict__ gcn_b,
              float* __restrict__ out)
{
    const int node = blockIdx.x;            // b*K + i
    const int b = node >> 10, i = node & 1023;
    const int tid = threadIdx.x;
    const float dcol = rsqrtf(deg[node]);
    const int off = offs[node], cnt = count[node];
    const ushort_t* hhb = hh + ((size_t)b * KDIM) * 4096;

    float acc[16];
    {   // self loop: norm = dinv[i]*1*dinv[i]
        const uint4* ph = (const uint4*)(hhb + (size_t)i * 4096 + tid * 16);
        uint4 a = ph[0], bb = ph[1];
        float tmp[16]; unpack8(a, tmp); unpack8(bb, tmp + 8);
        float nrm = dcol * dcol;
#pragma unroll
        for (int k = 0; k < 16; k++) acc[k] = tmp[k] * nrm;
    }
    for (int t = 0; t < cnt; t++) {
        int e = elist[(size_t)b * EDIM + off + t];
        int row = ei[(size_t)b * 2 * EDIM + e];
        float w = ew[(size_t)b * EDIM + e];
        float nrm = rsqrtf(deg[b * KDIM + row]) * w * dcol;
        const uint4* ph = (const uint4*)(hhb + (size_t)row * 4096 + tid * 16);
        uint4 a = ph[0], bb = ph[1];
        float tmp[16]; unpack8(a, tmp); unpack8(bb, tmp + 8);
#pragma unroll
        for (int k = 0; k < 16; k++) acc[k] += tmp[k] * nrm;
    }
    // out = xt + acc + gcn_b[d]
    const int d0 = (tid * 16) & 127;
    float4* po = (float4*)(out + (size_t)node * 4096 + tid * 16);
#pragma unroll
    for (int q = 0; q < 4; q++) {
        float4 xo = po[q];
        xo.x += acc[4 * q]     + gcn_b[d0 + 4 * q];
        xo.y += acc[4 * q + 1] + gcn_b[d0 + 4 * q + 1];
        xo.z += acc[4 * q + 2] + gcn_b[d0 + 4 * q + 2];
        xo.w += acc[4 * q + 3] + gcn_b[d0 + 4 * q + 3];
        po[q] = xo;
    }
}

// ---------------------------------------------------------------------------
extern "C" void kernel_launch(void* const* d_in, const int* in_sizes, int n_in,
                              void* d_out, int out_size, void* d_ws, size_t ws_size,
                              hipStream_t stream) {
    const float* x     = (const float*)d_in[0];
    const int*   ei    = (const int*)d_in[1];
    const float* ew    = (const float*)d_in[2];
    const float* w_qkv = (const float*)d_in[3];
    const float* b_qkv = (const float*)d_in[4];
    const float* w_out = (const float*)d_in[5];
    const float* b_out = (const float*)d_in[6];
    const float* w1    = (const float*)d_in[7];
    const float* b1    = (const float*)d_in[8];
    const float* w2    = (const float*)d_in[9];
    const float* b2    = (const float*)d_in[10];
    const float* ln1g  = (const float*)d_in[11];
    const float* ln1b  = (const float*)d_in[12];
    const float* ln2g  = (const float*)d_in[13];
    const float* ln2b  = (const float*)d_in[14];
    const float* gcnw  = (const float*)d_in[15];
    const float* gcnb  = (const float*)d_in[16];
    float* out = (float*)d_out;

    // ws layout (needs ~33.9 MB)
    char* ws = (char*)d_ws;
    ushort_t* hh  = (ushort_t*)ws;                       // 33,554,432 B (bf16 4096x4096)
    float*    deg = (float*)(ws + 33554432);             // 16 KB
    int*    count = (int*)(ws + 33554432 + 16384);       // 16 KB
    int*     offs = (int*)(ws + 33554432 + 32768);       // 16 KB
    int*   cursor = (int*)(ws + 33554432 + 49152);       // 16 KB
    int*    elist = (int*)(ws + 33554432 + 65536);       // 256 KB

    k_init<<<16, 256, 0, stream>>>(deg, count);
    k_transformer<<<NSEQ, 256, 0, stream>>>(x, w_qkv, b_qkv, w_out, b_out,
                                            w1, b1, w2, b2,
                                            ln1g, ln1b, ln2g, ln2b, gcnw, out, hh);
    k_degcount<<<256, 256, 0, stream>>>(ei, ew, deg, count);
    k_scan<<<BDIM, 1024, 0, stream>>>(count, offs, cursor);
    k_fill<<<256, 256, 0, stream>>>(ei, cursor, elist);
    k_gather<<<NSEQ, 256, 0, stream>>>(ei, ew, deg, offs, count, elist, hh, gcnb, out);
}

// Round 3
// 373.934 us; speedup vs baseline: 20.5978x; 20.5978x over previous
//
#include <hip/hip_runtime.h>
#include <hip/hip_bf16.h>

// Problem constants
#define BDIM 4
#define KDIM 1024
#define LDIM 32
#define DDIM 128
#define HDIM 8
#define DFFC 512
#define EDIM 16384
#define NSEQ (BDIM * KDIM)   // 4096

typedef unsigned short ushort_t;
typedef unsigned int   uint32;

typedef __bf16 bf16x8 __attribute__((ext_vector_type(8)));
typedef float  f32x4  __attribute__((ext_vector_type(4)));

#define MFMA(A, B, C) __builtin_amdgcn_mfma_f32_16x16x32_bf16((A), (B), (C), 0, 0, 0)

__device__ __forceinline__ float bf2f(uint32 u) {
    union { uint32 i; float f; } v; v.i = u << 16; return v.f;
}
__device__ __forceinline__ ushort_t f2bf(float f) {
    union { float f; uint32 i; } v; v.f = f;
    uint32 r = (v.i + 0x7fffu + ((v.i >> 16) & 1u)) >> 16;
    return (ushort_t)r;
}
__device__ __forceinline__ void unpack8(uint4 v, float* dst) {
    const uint32* pv = (const uint32*)&v;
#pragma unroll
    for (int q = 0; q < 4; q++) {
        uint32 w = pv[q];
        dst[2 * q]     = bf2f(w & 0xffffu);
        dst[2 * q + 1] = bf2f(w >> 16);
    }
}
// pack 16 floats -> 16 bf16 (32B) at p (16B-aligned)
__device__ __forceinline__ void store16bf(ushort_t* p, const float* v) {
    uint32 w[8];
#pragma unroll
    for (int q = 0; q < 8; q++)
        w[q] = (uint32)f2bf(v[2 * q]) | ((uint32)f2bf(v[2 * q + 1]) << 16);
    ((uint4*)p)[0] = make_uint4(w[0], w[1], w[2], w[3]);
    ((uint4*)p)[1] = make_uint4(w[4], w[5], w[6], w[7]);
}

// ---------------------------------------------------------------------------
// Weight pre-conversion fp32 -> bf16 into ws (concatenated, row-major as src):
//   wqkv [384][128] @0 | wout [128][128] @49152 | w1 [512][128] @65536
//   w2 [128][512] @131072 | gcnw [128][128] @196608   (elements)
// ---------------------------------------------------------------------------
#define NWCVT 212992
__global__ void k_prep(const float* __restrict__ wq, const float* __restrict__ wo,
                       const float* __restrict__ w1, const float* __restrict__ w2,
                       const float* __restrict__ wg, ushort_t* __restrict__ dst) {
    int i = blockIdx.x * 256 + threadIdx.x;
    if (i >= NWCVT) return;
    float v;
    if      (i <  49152) v = wq[i];
    else if (i <  65536) v = wo[i - 49152];
    else if (i < 131072) v = w1[i - 65536];
    else if (i < 196608) v = w2[i - 131072];
    else                 v = wg[i - 196608];
    dst[i] = f2bf(v);
}

// ---------------------------------------------------------------------------
// Fused transformer layer, MFMA edition. Block = 256 thr (4 waves) per sequence.
// LDS map (aliased; barriers between conflicting phases):
//   s_h  [32][136] bf16 @0       (h0 -> h1 -> h2; MFMA A source)
//   s_qk [32][264] bf16 @8704    (Q cols 0-127, K cols 128-255)
//   s_p  [32][264] bf16 @8704    (P, aliases s_qk after QK^T)
//   s_u  [32][132] f32  @8704    (attn-proj out, aliases after PV)
//   s_vt [128][40] bf16 @25600   (V transposed: [dh_global][key])
//   s_o  [32][136] bf16 @35840   (attention output)
//   s_f1 [32][536] bf16 @8704    (FFN1 out; spans to 43008)
//   s_f2 [32][132] f32  @43008   (FFN2 out)   total 59904 B
// ---------------------------------------------------------------------------
__global__ __launch_bounds__(256)
void k_transformer(const float* __restrict__ x,
                   const ushort_t* __restrict__ wq_bf, const float* __restrict__ b_qkv,
                   const ushort_t* __restrict__ wo_bf, const float* __restrict__ b_out,
                   const ushort_t* __restrict__ w1_bf, const float* __restrict__ b1,
                   const ushort_t* __restrict__ w2_bf, const float* __restrict__ b2,
                   const ushort_t* __restrict__ wg_bf,
                   const float* __restrict__ ln1g, const float* __restrict__ ln1b,
                   const float* __restrict__ ln2g, const float* __restrict__ ln2b,
                   float* __restrict__ out_xt, ushort_t* __restrict__ hh)
{
    const int n    = blockIdx.x;
    const int tid  = threadIdx.x;
    const int wave = tid >> 6;
    const int lane = tid & 63;
    const int lh   = lane & 15;      // M-row / N-col within 16x16 tile
    const int lg   = lane >> 4;      // k-group (8 elems each)
    const int l    = tid >> 3;       // per-thread row (LN phases)
    const int ts   = tid & 7;
    const int ds   = ts * 16;

    __shared__ __align__(16) char smem[59904];
    ushort_t* s_h  = (ushort_t*)(smem);
    ushort_t* s_qk = (ushort_t*)(smem + 8704);
    ushort_t* s_p  = (ushort_t*)(smem + 8704);
    float*    s_u  = (float*)(smem + 8704);
    ushort_t* s_vt = (ushort_t*)(smem + 25600);
    ushort_t* s_o  = (ushort_t*)(smem + 35840);
    ushort_t* s_f1 = (ushort_t*)(smem + 8704);
    float*    s_f2 = (float*)(smem + 43008);

    // ---- load h0 (fp32, thread owns row l cols ds..ds+16) + bf16 to s_h ----
    float h0[16];
    {
        const float4* px = (const float4*)(x + (size_t)n * 4096 + tid * 16);
#pragma unroll
        for (int q = 0; q < 4; q++) {
            float4 v = px[q];
            h0[4 * q] = v.x; h0[4 * q + 1] = v.y; h0[4 * q + 2] = v.z; h0[4 * q + 3] = v.w;
        }
    }
    store16bf(s_h + l * 136 + ds, h0);
    __syncthreads();

    // ================= QKV: [32x128] @ wqkv^T -> Q,K (s_qk) and V^T (s_vt) ==
    {
        bf16x8 af[2][4];
#pragma unroll
        for (int mt = 0; mt < 2; mt++)
#pragma unroll
            for (int kk = 0; kk < 4; kk++)
                af[mt][kk] = *(const bf16x8*)(s_h + (mt * 16 + lh) * 136 + kk * 32 + lg * 8);
        const int ntb = wave * 6;
#pragma unroll
        for (int j = 0; j < 6; j++) {
            const int nt = ntb + j;
            f32x4 a0 = {0.f, 0.f, 0.f, 0.f}, a1 = {0.f, 0.f, 0.f, 0.f};
#pragma unroll
            for (int kk = 0; kk < 4; kk++) {
                bf16x8 b = *(const bf16x8*)(wq_bf + (size_t)(nt * 16 + lh) * 128 + kk * 32 + lg * 8);
                a0 = MFMA(af[0][kk], b, a0);
                a1 = MFMA(af[1][kk], b, a1);
            }
            const int col = nt * 16 + lh;
            const float bias = b_qkv[col];
            if (nt < 16) {          // Q (0-127) and K (128-255) -> s_qk row-major
#pragma unroll
                for (int i = 0; i < 4; i++) {
                    s_qk[(lg * 4 + i) * 264 + col]      = f2bf(a0[i] + bias);
                    s_qk[(16 + lg * 4 + i) * 264 + col] = f2bf(a1[i] + bias);
                }
            } else {                // V -> transposed s_vt[dh_global][key]
                const int vc = col - 256;
#pragma unroll
                for (int i = 0; i < 4; i++) {
                    s_vt[vc * 40 + lg * 4 + i]      = f2bf(a0[i] + bias);
                    s_vt[vc * 40 + 16 + lg * 4 + i] = f2bf(a1[i] + bias);
                }
            }
        }
    }
    __syncthreads();

    // ================= QK^T (K=16 via zero-padded K=32), per-wave 2 heads ====
    f32x4 sA[2][2][2];   // [head][mt][nt]
    {
        bf16x8 bz = {};
#pragma unroll
        for (int hd = 0; hd < 2; hd++) {
            const int h8 = wave * 2 + hd;
#pragma unroll
            for (int mt = 0; mt < 2; mt++) {
                bf16x8 aq = *(const bf16x8*)(s_qk + (mt * 16 + lh) * 264 + h8 * 16 + (lg & 1) * 8);
#pragma unroll
                for (int nt = 0; nt < 2; nt++) {
                    bf16x8 bk = bz;
                    if (lg < 2)
                        bk = *(const bf16x8*)(s_qk + (nt * 16 + lh) * 264 + 128 + h8 * 16 + lg * 8);
                    f32x4 z = {0.f, 0.f, 0.f, 0.f};
                    sA[hd][mt][nt] = MFMA(aq, bk, z);
                }
            }
        }
    }

    // ---- softmax in registers (rows split over lane&15 cols + 2 nt regs) ----
    ushort_t pv[2][16];
#pragma unroll
    for (int hd = 0; hd < 2; hd++) {
#pragma unroll
        for (int mt = 0; mt < 2; mt++) {
#pragma unroll
            for (int i = 0; i < 4; i++) {
                float v0 = sA[hd][mt][0][i] * 0.25f;   // 1/sqrt(dh=16)
                float v1 = sA[hd][mt][1][i] * 0.25f;
                float mx = fmaxf(v0, v1);
#pragma unroll
                for (int m = 1; m < 16; m <<= 1) mx = fmaxf(mx, __shfl_xor(mx, m));
                float e0 = __expf(v0 - mx), e1 = __expf(v1 - mx);
                float sm = e0 + e1;
#pragma unroll
                for (int m = 1; m < 16; m <<= 1) sm += __shfl_xor(sm, m);
                float inv = 1.0f / sm;
                pv[hd][mt * 8 + i]     = f2bf(e0 * inv);
                pv[hd][mt * 8 + 4 + i] = f2bf(e1 * inv);
            }
        }
    }
    __syncthreads();   // all QK^T reads of s_qk complete -> safe to write P
#pragma unroll
    for (int hd = 0; hd < 2; hd++) {
        const int h8 = wave * 2 + hd;
#pragma unroll
        for (int mt = 0; mt < 2; mt++)
#pragma unroll
            for (int nt = 0; nt < 2; nt++)
#pragma unroll
                for (int i = 0; i < 4; i++)
                    s_p[(mt * 16 + lg * 4 + i) * 264 + h8 * 32 + nt * 16 + lh] =
                        pv[hd][mt * 8 + nt * 4 + i];
    }
    __syncthreads();

    // ================= PV: P[32x32] @ V[32x16] per head ======================
    {
#pragma unroll
        for (int hd = 0; hd < 2; hd++) {
            const int h8 = wave * 2 + hd;
            bf16x8 bv = *(const bf16x8*)(s_vt + (h8 * 16 + lh) * 40 + lg * 8);
#pragma unroll
            for (int mt = 0; mt < 2; mt++) {
                bf16x8 ap = *(const bf16x8*)(s_p + (mt * 16 + lh) * 264 + h8 * 32 + lg * 8);
                f32x4 z = {0.f, 0.f, 0.f, 0.f};
                f32x4 o = MFMA(ap, bv, z);
#pragma unroll
                for (int i = 0; i < 4; i++)
                    s_o[(mt * 16 + lg * 4 + i) * 136 + h8 * 16 + lh] = f2bf(o[i]);
            }
        }
    }
    __syncthreads();

    // ================= W_out: o[32x128] @ wout^T + b -> s_u (fp32) ===========
    {
        bf16x8 af[2][4];
#pragma unroll
        for (int mt = 0; mt < 2; mt++)
#pragma unroll
            for (int kk = 0; kk < 4; kk++)
                af[mt][kk] = *(const bf16x8*)(s_o + (mt * 16 + lh) * 136 + kk * 32 + lg * 8);
#pragma unroll
        for (int j = 0; j < 2; j++) {
            const int nt = wave * 2 + j;
            f32x4 a0 = {0.f, 0.f, 0.f, 0.f}, a1 = {0.f, 0.f, 0.f, 0.f};
#pragma unroll
            for (int kk = 0; kk < 4; kk++) {
                bf16x8 b = *(const bf16x8*)(wo_bf + (size_t)(nt * 16 + lh) * 128 + kk * 32 + lg * 8);
                a0 = MFMA(af[0][kk], b, a0);
                a1 = MFMA(af[1][kk], b, a1);
            }
            const int col = nt * 16 + lh;
            const float bias = b_out[col];
#pragma unroll
            for (int i = 0; i < 4; i++) {
                s_u[(lg * 4 + i) * 132 + col]      = a0[i] + bias;
                s_u[(16 + lg * 4 + i) * 132 + col] = a1[i] + bias;
            }
        }
    }
    __syncthreads();

    // ================= LN1 (per-thread row layout) ===========================
    float h1[16];
    {
        float t[16]; float sum = 0.f;
#pragma unroll
        for (int i = 0; i < 16; i++) { t[i] = h0[i] + s_u[l * 132 + ds + i]; sum += t[i]; }
        sum += __shfl_xor(sum, 1); sum += __shfl_xor(sum, 2); sum += __shfl_xor(sum, 4);
        float mean = sum * (1.f / 128.f);
        float vs = 0.f;
#pragma unroll
        for (int i = 0; i < 16; i++) { float d = t[i] - mean; vs += d * d; }
        vs += __shfl_xor(vs, 1); vs += __shfl_xor(vs, 2); vs += __shfl_xor(vs, 4);
        float rs = rsqrtf(vs * (1.f / 128.f) + 1e-5f);
#pragma unroll
        for (int i = 0; i < 16; i++)
            h1[i] = (t[i] - mean) * rs * ln1g[ds + i] + ln1b[ds + i];
    }
    store16bf(s_h + l * 136 + ds, h1);
    __syncthreads();   // s_u reads + s_h writes done; s_f1 may now overwrite

    // ================= FFN1: h1[32x128] @ w1^T, relu -> s_f1 bf16 ============
    {
        bf16x8 af[2][4];
#pragma unroll
        for (int mt = 0; mt < 2; mt++)
#pragma unroll
            for (int kk = 0; kk < 4; kk++)
                af[mt][kk] = *(const bf16x8*)(s_h + (mt * 16 + lh) * 136 + kk * 32 + lg * 8);
        const int ntb = wave * 8;
#pragma unroll
        for (int j = 0; j < 8; j++) {
            const int nt = ntb + j;
            f32x4 a0 = {0.f, 0.f, 0.f, 0.f}, a1 = {0.f, 0.f, 0.f, 0.f};
#pragma unroll
            for (int kk = 0; kk < 4; kk++) {
                bf16x8 b = *(const bf16x8*)(w1_bf + (size_t)(nt * 16 + lh) * 128 + kk * 32 + lg * 8);
                a0 = MFMA(af[0][kk], b, a0);
                a1 = MFMA(af[1][kk], b, a1);
            }
            const int col = nt * 16 + lh;
            const float bias = b1[col];
#pragma unroll
            for (int i = 0; i < 4; i++) {
                s_f1[(lg * 4 + i) * 536 + col]      = f2bf(fmaxf(a0[i] + bias, 0.f));
                s_f1[(16 + lg * 4 + i) * 536 + col] = f2bf(fmaxf(a1[i] + bias, 0.f));
            }
        }
    }
    __syncthreads();

    // ================= FFN2: f1[32x512] @ w2^T + b2 -> s_f2 fp32 =============
    {
        f32x4 f00 = {0.f,0.f,0.f,0.f}, f01 = {0.f,0.f,0.f,0.f};
        f32x4 f10 = {0.f,0.f,0.f,0.f}, f11 = {0.f,0.f,0.f,0.f};
        const int col0 = wave * 32 + lh, col1 = col0 + 16;
#pragma unroll 4
        for (int kk = 0; kk < 16; kk++) {
            bf16x8 a0 = *(const bf16x8*)(s_f1 + lh * 536 + kk * 32 + lg * 8);
            bf16x8 a1 = *(const bf16x8*)(s_f1 + (16 + lh) * 536 + kk * 32 + lg * 8);
            bf16x8 b0 = *(const bf16x8*)(w2_bf + (size_t)col0 * 512 + kk * 32 + lg * 8);
            bf16x8 b1v = *(const bf16x8*)(w2_bf + (size_t)col1 * 512 + kk * 32 + lg * 8);
            f00 = MFMA(a0, b0, f00);  f01 = MFMA(a1, b0, f01);
            f10 = MFMA(a0, b1v, f10); f11 = MFMA(a1, b1v, f11);
        }
        const float bi0 = b2[col0], bi1 = b2[col1];
#pragma unroll
        for (int i = 0; i < 4; i++) {
            s_f2[(lg * 4 + i) * 132 + col0]      = f00[i] + bi0;
            s_f2[(16 + lg * 4 + i) * 132 + col0] = f01[i] + bi0;
            s_f2[(lg * 4 + i) * 132 + col1]      = f10[i] + bi1;
            s_f2[(16 + lg * 4 + i) * 132 + col1] = f11[i] + bi1;
        }
    }
    __syncthreads();

    // ================= LN2, out write, h2 -> s_h =============================
    float h2[16];
    {
        float t[16]; float sum = 0.f;
#pragma unroll
        for (int i = 0; i < 16; i++) { t[i] = h1[i] + s_f2[l * 132 + ds + i]; sum += t[i]; }
        sum += __shfl_xor(sum, 1); sum += __shfl_xor(sum, 2); sum += __shfl_xor(sum, 4);
        float mean = sum * (1.f / 128.f);
        float vs = 0.f;
#pragma unroll
        for (int i = 0; i < 16; i++) { float d = t[i] - mean; vs += d * d; }
        vs += __shfl_xor(vs, 1); vs += __shfl_xor(vs, 2); vs += __shfl_xor(vs, 4);
        float rs = rsqrtf(vs * (1.f / 128.f) + 1e-5f);
#pragma unroll
        for (int i = 0; i < 16; i++)
            h2[i] = (t[i] - mean) * rs * ln2g[ds + i] + ln2b[ds + i];
    }
    {
        float4* po = (float4*)(out_xt + (size_t)n * 4096 + tid * 16);
#pragma unroll
        for (int q = 0; q < 4; q++)
            po[q] = make_float4(h2[4 * q], h2[4 * q + 1], h2[4 * q + 2], h2[4 * q + 3]);
    }
    store16bf(s_h + l * 136 + ds, h2);
    __syncthreads();

    // ================= GCN weight GEMM: hh = h2 @ gcnw^T (bf16 out) ==========
    {
        bf16x8 af[2][4];
#pragma unroll
        for (int mt = 0; mt < 2; mt++)
#pragma unroll
            for (int kk = 0; kk < 4; kk++)
                af[mt][kk] = *(const bf16x8*)(s_h + (mt * 16 + lh) * 136 + kk * 32 + lg * 8);
#pragma unroll
        for (int j = 0; j < 2; j++) {
            const int nt = wave * 2 + j;
            f32x4 a0 = {0.f, 0.f, 0.f, 0.f}, a1 = {0.f, 0.f, 0.f, 0.f};
#pragma unroll
            for (int kk = 0; kk < 4; kk++) {
                bf16x8 b = *(const bf16x8*)(wg_bf + (size_t)(nt * 16 + lh) * 128 + kk * 32 + lg * 8);
                a0 = MFMA(af[0][kk], b, a0);
                a1 = MFMA(af[1][kk], b, a1);
            }
            const int col = nt * 16 + lh;
            ushort_t* hp = hh + (size_t)n * 4096;
#pragma unroll
            for (int i = 0; i < 4; i++) {
                hp[(lg * 4 + i) * 128 + col]      = f2bf(a0[i]);
                hp[(16 + lg * 4 + i) * 128 + col] = f2bf(a1[i]);
            }
        }
    }
}

// ---------------------------------------------------------------------------
// GCN support kernels (unchanged from round 2)
// ---------------------------------------------------------------------------
__global__ void k_init(float* deg, int* count) {
    int i = blockIdx.x * 256 + threadIdx.x;
    if (i < BDIM * KDIM) { deg[i] = 1.0f; count[i] = 0; }
}

__global__ void k_degcount(const int* __restrict__ ei, const float* __restrict__ ew,
                           float* deg, int* count) {
    int idx = blockIdx.x * 256 + threadIdx.x;
    if (idx >= BDIM * EDIM) return;
    int b = idx / EDIM, e = idx - b * EDIM;
    int col = ei[(size_t)b * 2 * EDIM + EDIM + e];
    float w = ew[(size_t)b * EDIM + e];
    atomicAdd(&deg[b * KDIM + col], w);
    atomicAdd(&count[b * KDIM + col], 1);
}

__global__ __launch_bounds__(1024)
void k_scan(const int* __restrict__ count, int* offs, int* cursor) {
    __shared__ int s[KDIM];
    int b = blockIdx.x, i = threadIdx.x;
    int c = count[b * KDIM + i];
    s[i] = c; __syncthreads();
#pragma unroll 1
    for (int off = 1; off < KDIM; off <<= 1) {
        int t = (i >= off) ? s[i - off] : 0;
        __syncthreads();
        s[i] += t;
        __syncthreads();
    }
    int excl = s[i] - c;
    offs[b * KDIM + i] = excl;
    cursor[b * KDIM + i] = excl;
}

__global__ void k_fill(const int* __restrict__ ei, int* cursor, int* elist) {
    int idx = blockIdx.x * 256 + threadIdx.x;
    if (idx >= BDIM * EDIM) return;
    int b = idx / EDIM, e = idx - b * EDIM;
    int col = ei[(size_t)b * 2 * EDIM + EDIM + e];
    int pos = atomicAdd(&cursor[b * KDIM + col], 1);
    elist[(size_t)b * EDIM + pos] = e;
}

__global__ __launch_bounds__(256)
void k_gather(const int* __restrict__ ei, const float* __restrict__ ew,
              const float* __restrict__ deg, const int* __restrict__ offs,
              const int* __restrict__ count, const int* __restrict__ elist,
              const ushort_t* __restrict__ hh, const float* __restrict__ gcn_b,
              float* __restrict__ out)
{
    const int node = blockIdx.x;
    const int b = node >> 10, i = node & 1023;
    const int tid = threadIdx.x;
    const float dcol = rsqrtf(deg[node]);
    const int off = offs[node], cnt = count[node];
    const ushort_t* hhb = hh + ((size_t)b * KDIM) * 4096;

    float acc[16];
    {
        const uint4* ph = (const uint4*)(hhb + (size_t)i * 4096 + tid * 16);
        uint4 a = ph[0], bb = ph[1];
        float tmp[16]; unpack8(a, tmp); unpack8(bb, tmp + 8);
        float nrm = dcol * dcol;
#pragma unroll
        for (int k = 0; k < 16; k++) acc[k] = tmp[k] * nrm;
    }
    for (int t = 0; t < cnt; t++) {
        int e = elist[(size_t)b * EDIM + off + t];
        int row = ei[(size_t)b * 2 * EDIM + e];
        float w = ew[(size_t)b * EDIM + e];
        float nrm = rsqrtf(deg[b * KDIM + row]) * w * dcol;
        const uint4* ph = (const uint4*)(hhb + (size_t)row * 4096 + tid * 16);
        uint4 a = ph[0], bb = ph[1];
        float tmp[16]; unpack8(a, tmp); unpack8(bb, tmp + 8);
#pragma unroll
        for (int k = 0; k < 16; k++) acc[k] += tmp[k] * nrm;
    }
    const int d0 = (tid * 16) & 127;
    float4* po = (float4*)(out + (size_t)node * 4096 + tid * 16);
#pragma unroll
    for (int q = 0; q < 4; q++) {
        float4 xo = po[q];
        xo.x += acc[4 * q]     + gcn_b[d0 + 4 * q];
        xo.y += acc[4 * q + 1] + gcn_b[d0 + 4 * q + 1];
        xo.z += acc[4 * q + 2] + gcn_b[d0 + 4 * q + 2];
        xo.w += acc[4 * q + 3] + gcn_b[d0 + 4 * q + 3];
        po[q] = xo;
    }
}

// ---------------------------------------------------------------------------
extern "C" void kernel_launch(void* const* d_in, const int* in_sizes, int n_in,
                              void* d_out, int out_size, void* d_ws, size_t ws_size,
                              hipStream_t stream) {
    const float* x     = (const float*)d_in[0];
    const int*   ei    = (const int*)d_in[1];
    const float* ew    = (const float*)d_in[2];
    const float* w_qkv = (const float*)d_in[3];
    const float* b_qkv = (const float*)d_in[4];
    const float* w_out = (const float*)d_in[5];
    const float* b_out = (const float*)d_in[6];
    const float* w1    = (const float*)d_in[7];
    const float* b1    = (const float*)d_in[8];
    const float* w2    = (const float*)d_in[9];
    const float* b2    = (const float*)d_in[10];
    const float* ln1g  = (const float*)d_in[11];
    const float* ln1b  = (const float*)d_in[12];
    const float* ln2g  = (const float*)d_in[13];
    const float* ln2b  = (const float*)d_in[14];
    const float* gcnw  = (const float*)d_in[15];
    const float* gcnb  = (const float*)d_in[16];
    float* out = (float*)d_out;

    // ws layout (bytes):
    //   0        : bf16 weights, 425984
    //   425984   : deg   (16384)
    //   442368   : count (16384)
    //   458752   : offs  (16384)
    //   475136   : cursor(16384)
    //   491520   : elist (262144)
    //   753664   : hh bf16 [4096][4096] (33554432)  -> total 34,308,096
    char* ws = (char*)d_ws;
    ushort_t* wbf   = (ushort_t*)ws;
    ushort_t* wq_bf = wbf;
    ushort_t* wo_bf = wbf + 49152;
    ushort_t* w1_bf = wbf + 65536;
    ushort_t* w2_bf = wbf + 131072;
    ushort_t* wg_bf = wbf + 196608;
    float*    deg   = (float*)(ws + 425984);
    int*      count = (int*)(ws + 442368);
    int*      offs  = (int*)(ws + 458752);
    int*      cursor= (int*)(ws + 475136);
    int*      elist = (int*)(ws + 491520);
    ushort_t* hh    = (ushort_t*)(ws + 753664);

    k_prep<<<(NWCVT + 255) / 256, 256, 0, stream>>>(w_qkv, w_out, w1, w2, gcnw, wbf);
    k_init<<<16, 256, 0, stream>>>(deg, count);
    k_transformer<<<NSEQ, 256, 0, stream>>>(x, wq_bf, b_qkv, wo_bf, b_out,
                                            w1_bf, b1, w2_bf, b2, wg_bf,
                                            ln1g, ln1b, ln2g, ln2b, out, hh);
    k_degcount<<<256, 256, 0, stream>>>(ei, ew, deg, count);
    k_scan<<<BDIM, 1024, 0, stream>>>(count, offs, cursor);
    k_fill<<<256, 256, 0, stream>>>(ei, cursor, elist);
    k_gather<<<NSEQ, 256, 0, stream>>>(ei, ew, deg, offs, count, elist, hh, gcnb, out);
}

// Round 4
// 357.572 us; speedup vs baseline: 21.5403x; 1.0458x over previous
//
#include <hip/hip_runtime.h>
#include <hip/hip_bf16.h>

// Problem constants
#define BDIM 4
#define KDIM 1024
#define LDIM 32
#define DDIM 128
#define HDIM 8
#define DFFC 512
#define EDIM 16384
#define NSEQ (BDIM * KDIM)   // 4096

typedef unsigned short ushort_t;
typedef unsigned int   uint32;

typedef __bf16 bf16x8 __attribute__((ext_vector_type(8)));
typedef float  f32x4  __attribute__((ext_vector_type(4)));

#define MFMA(A, B, C) __builtin_amdgcn_mfma_f32_16x16x32_bf16((A), (B), (C), 0, 0, 0)

__device__ __forceinline__ float bf2f(uint32 u) {
    union { uint32 i; float f; } v; v.i = u << 16; return v.f;
}
__device__ __forceinline__ ushort_t f2bf(float f) {
    union { float f; uint32 i; } v; v.f = f;
    uint32 r = (v.i + 0x7fffu + ((v.i >> 16) & 1u)) >> 16;
    return (ushort_t)r;
}
// hardware packed cvt: returns {lo=bf16(a), hi=bf16(b)}
__device__ __forceinline__ uint32 cvtpk(float a, float b) {
    uint32 r;
    asm("v_cvt_pk_bf16_f32 %0, %1, %2" : "=v"(r) : "v"(a), "v"(b));
    return r;
}
__device__ __forceinline__ void unpack8(uint4 v, float* dst) {
    const uint32* pv = (const uint32*)&v;
#pragma unroll
    for (int q = 0; q < 4; q++) {
        uint32 w = pv[q];
        dst[2 * q]     = bf2f(w & 0xffffu);
        dst[2 * q + 1] = bf2f(w >> 16);
    }
}
// pack 16 floats -> 16 bf16 (32B) at p (16B-aligned)
__device__ __forceinline__ void store16bf(ushort_t* p, const float* v) {
    uint32 w[8];
#pragma unroll
    for (int q = 0; q < 8; q++) w[q] = cvtpk(v[2 * q], v[2 * q + 1]);
    ((uint4*)p)[0] = make_uint4(w[0], w[1], w[2], w[3]);
    ((uint4*)p)[1] = make_uint4(w[4], w[5], w[6], w[7]);
}

// ---------------------------------------------------------------------------
// Weight pre-conversion fp32 -> bf16 into ws:
//   wqkv [384][128] @0 | wout [128][128] @49152 | w1 [512][128] @65536
//   w2 [128][512] @131072 | gcnw [128][128] @196608   (elements)
// ---------------------------------------------------------------------------
#define NWCVT 212992
__global__ void k_prep(const float* __restrict__ wq, const float* __restrict__ wo,
                       const float* __restrict__ w1, const float* __restrict__ w2,
                       const float* __restrict__ wg, ushort_t* __restrict__ dst) {
    int i = blockIdx.x * 256 + threadIdx.x;
    if (i >= NWCVT) return;
    float v;
    if      (i <  49152) v = wq[i];
    else if (i <  65536) v = wo[i - 49152];
    else if (i < 131072) v = w1[i - 65536];
    else if (i < 196608) v = w2[i - 131072];
    else                 v = wg[i - 196608];
    dst[i] = f2bf(v);
}

// ---------------------------------------------------------------------------
// Fused transformer layer, MFMA edition v2. Block = 256 thr (4 waves)/sequence.
// LDS map (35840 B total -> 4 blocks/CU):
//   regionH @0     [32][136] bf16 (8704):  s_h (h0/h1/h2 A-src)  <-> s_o (attn out)
//   regionM @8704  (16896): s_qk [32][264] bf16 (Q|K) -> s_p -> s_u f32 [32][132]
//                           -> s_f1 [32][264] bf16 (FFN half) -> s_f2 f32 [32][132]
//   s_vt  @25600  [128][40] bf16 (10240): V transposed [dh_global][key]
// ---------------------------------------------------------------------------
__global__ __launch_bounds__(256)
void k_transformer(const float* __restrict__ x,
                   const ushort_t* __restrict__ wq_bf, const float* __restrict__ b_qkv,
                   const ushort_t* __restrict__ wo_bf, const float* __restrict__ b_out,
                   const ushort_t* __restrict__ w1_bf, const float* __restrict__ b1,
                   const ushort_t* __restrict__ w2_bf, const float* __restrict__ b2,
                   const ushort_t* __restrict__ wg_bf,
                   const float* __restrict__ ln1g, const float* __restrict__ ln1b,
                   const float* __restrict__ ln2g, const float* __restrict__ ln2b,
                   float* __restrict__ out_xt, ushort_t* __restrict__ hh)
{
    const int n    = blockIdx.x;
    const int tid  = threadIdx.x;
    const int wave = tid >> 6;
    const int lane = tid & 63;
    const int lh   = lane & 15;      // M-row / N-col within 16x16 tile
    const int lg   = lane >> 4;      // k-group (8 elems each)
    const int l    = tid >> 3;       // per-thread row (LN phases)
    const int ds   = (tid & 7) * 16;

    __shared__ __align__(16) char smem[35840];
    ushort_t* s_h  = (ushort_t*)(smem);            // aliases s_o
    ushort_t* s_o  = (ushort_t*)(smem);
    ushort_t* s_qk = (ushort_t*)(smem + 8704);     // aliases s_p/s_u/s_f1/s_f2
    ushort_t* s_p  = (ushort_t*)(smem + 8704);
    float*    s_u  = (float*)(smem + 8704);
    ushort_t* s_f1 = (ushort_t*)(smem + 8704);
    float*    s_f2 = (float*)(smem + 8704);
    ushort_t* s_vt = (ushort_t*)(smem + 25600);

    // ---- load h0 (fp32, thread owns row l cols ds..ds+16) + bf16 to s_h ----
    float h0[16];
    {
        const float4* px = (const float4*)(x + (size_t)n * 4096 + tid * 16);
#pragma unroll
        for (int q = 0; q < 4; q++) {
            float4 v = px[q];
            h0[4 * q] = v.x; h0[4 * q + 1] = v.y; h0[4 * q + 2] = v.z; h0[4 * q + 3] = v.w;
        }
    }
    store16bf(s_h + l * 136 + ds, h0);
    __syncthreads();

    // ================= QKV: [32x128] @ wqkv^T -> Q,K (s_qk) and V^T (s_vt) ==
    {
        bf16x8 af[2][4];
#pragma unroll
        for (int mt = 0; mt < 2; mt++)
#pragma unroll
            for (int kk = 0; kk < 4; kk++)
                af[mt][kk] = *(const bf16x8*)(s_h + (mt * 16 + lh) * 136 + kk * 32 + lg * 8);
        const int ntb = wave * 6;
#pragma unroll
        for (int j = 0; j < 6; j++) {
            const int nt = ntb + j;
            f32x4 a0 = {0.f, 0.f, 0.f, 0.f}, a1 = {0.f, 0.f, 0.f, 0.f};
#pragma unroll
            for (int kk = 0; kk < 4; kk++) {
                bf16x8 b = *(const bf16x8*)(wq_bf + (size_t)(nt * 16 + lh) * 128 + kk * 32 + lg * 8);
                a0 = MFMA(af[0][kk], b, a0);
                a1 = MFMA(af[1][kk], b, a1);
            }
            const int col = nt * 16 + lh;
            const float bias = b_qkv[col];
            uint32 p01 = cvtpk(a0[0] + bias, a0[1] + bias);
            uint32 p23 = cvtpk(a0[2] + bias, a0[3] + bias);
            uint32 q01 = cvtpk(a1[0] + bias, a1[1] + bias);
            uint32 q23 = cvtpk(a1[2] + bias, a1[3] + bias);
            if (nt < 16) {          // Q (cols 0-127) and K (cols 128-255)
                const int r0 = lg * 4;
                s_qk[(r0 + 0) * 264 + col] = (ushort_t)p01;
                s_qk[(r0 + 1) * 264 + col] = (ushort_t)(p01 >> 16);
                s_qk[(r0 + 2) * 264 + col] = (ushort_t)p23;
                s_qk[(r0 + 3) * 264 + col] = (ushort_t)(p23 >> 16);
                s_qk[(16 + r0 + 0) * 264 + col] = (ushort_t)q01;
                s_qk[(16 + r0 + 1) * 264 + col] = (ushort_t)(q01 >> 16);
                s_qk[(16 + r0 + 2) * 264 + col] = (ushort_t)q23;
                s_qk[(16 + r0 + 3) * 264 + col] = (ushort_t)(q23 >> 16);
            } else {                // V -> transposed s_vt[dh_global][key]
                const int vc = col - 256;
                *(uint32*)&s_vt[vc * 40 + lg * 4]          = p01;
                *(uint32*)&s_vt[vc * 40 + lg * 4 + 2]      = p23;
                *(uint32*)&s_vt[vc * 40 + 16 + lg * 4]     = q01;
                *(uint32*)&s_vt[vc * 40 + 16 + lg * 4 + 2] = q23;
            }
        }
    }
    __syncthreads();

    // ================= QK^T (K=16 via zero-padded K=32), per-wave 2 heads ====
    f32x4 sA[2][2][2];   // [head][mt][nt]
    {
        bf16x8 bz = {};
#pragma unroll
        for (int hd = 0; hd < 2; hd++) {
            const int h8 = wave * 2 + hd;
#pragma unroll
            for (int mt = 0; mt < 2; mt++) {
                bf16x8 aq = *(const bf16x8*)(s_qk + (mt * 16 + lh) * 264 + h8 * 16 + (lg & 1) * 8);
#pragma unroll
                for (int nt = 0; nt < 2; nt++) {
                    bf16x8 bk = bz;
                    if (lg < 2)
                        bk = *(const bf16x8*)(s_qk + (nt * 16 + lh) * 264 + 128 + h8 * 16 + lg * 8);
                    f32x4 z = {0.f, 0.f, 0.f, 0.f};
                    sA[hd][mt][nt] = MFMA(aq, bk, z);
                }
            }
        }
    }

    // ---- softmax in registers ----
    float pvf[2][16];
#pragma unroll
    for (int hd = 0; hd < 2; hd++) {
#pragma unroll
        for (int mt = 0; mt < 2; mt++) {
#pragma unroll
            for (int i = 0; i < 4; i++) {
                float v0 = sA[hd][mt][0][i] * 0.25f;   // 1/sqrt(dh=16)
                float v1 = sA[hd][mt][1][i] * 0.25f;
                float mx = fmaxf(v0, v1);
#pragma unroll
                for (int m = 1; m < 16; m <<= 1) mx = fmaxf(mx, __shfl_xor(mx, m));
                float e0 = __expf(v0 - mx), e1 = __expf(v1 - mx);
                float sm = e0 + e1;
#pragma unroll
                for (int m = 1; m < 16; m <<= 1) sm += __shfl_xor(sm, m);
                float inv = 1.0f / sm;
                pvf[hd][mt * 8 + i]     = e0 * inv;
                pvf[hd][mt * 8 + 4 + i] = e1 * inv;
            }
        }
    }
    __syncthreads();   // all QK^T reads of s_qk complete -> safe to write P
#pragma unroll
    for (int hd = 0; hd < 2; hd++) {
        const int h8 = wave * 2 + hd;
#pragma unroll
        for (int mt = 0; mt < 2; mt++)
#pragma unroll
            for (int nt = 0; nt < 2; nt++) {
                uint32 r01 = cvtpk(pvf[hd][mt * 8 + nt * 4 + 0], pvf[hd][mt * 8 + nt * 4 + 1]);
                uint32 r23 = cvtpk(pvf[hd][mt * 8 + nt * 4 + 2], pvf[hd][mt * 8 + nt * 4 + 3]);
                const int r0 = mt * 16 + lg * 4, c = h8 * 32 + nt * 16 + lh;
                s_p[(r0 + 0) * 264 + c] = (ushort_t)r01;
                s_p[(r0 + 1) * 264 + c] = (ushort_t)(r01 >> 16);
                s_p[(r0 + 2) * 264 + c] = (ushort_t)r23;
                s_p[(r0 + 3) * 264 + c] = (ushort_t)(r23 >> 16);
            }
    }
    __syncthreads();

    // ================= PV: P[32x32] @ V[32x16] per head -> s_o (@regionH) ====
#pragma unroll
    for (int hd = 0; hd < 2; hd++) {
        const int h8 = wave * 2 + hd;
        bf16x8 bv = *(const bf16x8*)(s_vt + (h8 * 16 + lh) * 40 + lg * 8);
#pragma unroll
        for (int mt = 0; mt < 2; mt++) {
            bf16x8 ap = *(const bf16x8*)(s_p + (mt * 16 + lh) * 264 + h8 * 32 + lg * 8);
            f32x4 z = {0.f, 0.f, 0.f, 0.f};
            f32x4 o = MFMA(ap, bv, z);
            uint32 r01 = cvtpk(o[0], o[1]);
            uint32 r23 = cvtpk(o[2], o[3]);
            const int r0 = mt * 16 + lg * 4, c = h8 * 16 + lh;
            s_o[(r0 + 0) * 136 + c] = (ushort_t)r01;
            s_o[(r0 + 1) * 136 + c] = (ushort_t)(r01 >> 16);
            s_o[(r0 + 2) * 136 + c] = (ushort_t)r23;
            s_o[(r0 + 3) * 136 + c] = (ushort_t)(r23 >> 16);
        }
    }
    __syncthreads();

    // ================= W_out: o[32x128] @ wout^T + b -> s_u (fp32) ===========
    {
        bf16x8 af[2][4];
#pragma unroll
        for (int mt = 0; mt < 2; mt++)
#pragma unroll
            for (int kk = 0; kk < 4; kk++)
                af[mt][kk] = *(const bf16x8*)(s_o + (mt * 16 + lh) * 136 + kk * 32 + lg * 8);
#pragma unroll
        for (int j = 0; j < 2; j++) {
            const int nt = wave * 2 + j;
            f32x4 a0 = {0.f, 0.f, 0.f, 0.f}, a1 = {0.f, 0.f, 0.f, 0.f};
#pragma unroll
            for (int kk = 0; kk < 4; kk++) {
                bf16x8 b = *(const bf16x8*)(wo_bf + (size_t)(nt * 16 + lh) * 128 + kk * 32 + lg * 8);
                a0 = MFMA(af[0][kk], b, a0);
                a1 = MFMA(af[1][kk], b, a1);
            }
            const int col = nt * 16 + lh;
            const float bias = b_out[col];
#pragma unroll
            for (int i = 0; i < 4; i++) {
                s_u[(lg * 4 + i) * 132 + col]      = a0[i] + bias;
                s_u[(16 + lg * 4 + i) * 132 + col] = a1[i] + bias;
            }
        }
    }
    __syncthreads();

    // ================= LN1 (per-thread row layout) ===========================
    float h1[16];
    {
        float t[16]; float sum = 0.f;
#pragma unroll
        for (int i = 0; i < 16; i++) { t[i] = h0[i] + s_u[l * 132 + ds + i]; sum += t[i]; }
        sum += __shfl_xor(sum, 1); sum += __shfl_xor(sum, 2); sum += __shfl_xor(sum, 4);
        float mean = sum * (1.f / 128.f);
        float vs = 0.f;
#pragma unroll
        for (int i = 0; i < 16; i++) { float d = t[i] - mean; vs += d * d; }
        vs += __shfl_xor(vs, 1); vs += __shfl_xor(vs, 2); vs += __shfl_xor(vs, 4);
        float rs = rsqrtf(vs * (1.f / 128.f) + 1e-5f);
#pragma unroll
        for (int i = 0; i < 16; i++)
            h1[i] = (t[i] - mean) * rs * ln1g[ds + i] + ln1b[ds + i];
    }
    store16bf(s_h + l * 136 + ds, h1);   // overwrites s_o (reads done)
    __syncthreads();

    // ================= FFN (two K=256 rounds, acc in regs) ===================
    f32x4 f00 = {0.f,0.f,0.f,0.f}, f01 = {0.f,0.f,0.f,0.f};
    f32x4 f10 = {0.f,0.f,0.f,0.f}, f11 = {0.f,0.f,0.f,0.f};
    const int col0 = wave * 32 + lh, col1 = col0 + 16;
    bf16x8 ah[2][4];
#pragma unroll
    for (int mt = 0; mt < 2; mt++)
#pragma unroll
        for (int kk = 0; kk < 4; kk++)
            ah[mt][kk] = *(const bf16x8*)(s_h + (mt * 16 + lh) * 136 + kk * 32 + lg * 8);

#pragma unroll
    for (int r = 0; r < 2; r++) {
        // ---- FFN1 half: cols [r*256, r*256+256) -> s_f1 [32][264] ----
#pragma unroll
        for (int j = 0; j < 4; j++) {
            const int ntg = r * 16 + wave * 4 + j;
            f32x4 a0 = {0.f, 0.f, 0.f, 0.f}, a1 = {0.f, 0.f, 0.f, 0.f};
#pragma unroll
            for (int kk = 0; kk < 4; kk++) {
                bf16x8 b = *(const bf16x8*)(w1_bf + (size_t)(ntg * 16 + lh) * 128 + kk * 32 + lg * 8);
                a0 = MFMA(ah[0][kk], b, a0);
                a1 = MFMA(ah[1][kk], b, a1);
            }
            const float bias = b1[ntg * 16 + lh];
            uint32 p01 = cvtpk(fmaxf(a0[0] + bias, 0.f), fmaxf(a0[1] + bias, 0.f));
            uint32 p23 = cvtpk(fmaxf(a0[2] + bias, 0.f), fmaxf(a0[3] + bias, 0.f));
            uint32 q01 = cvtpk(fmaxf(a1[0] + bias, 0.f), fmaxf(a1[1] + bias, 0.f));
            uint32 q23 = cvtpk(fmaxf(a1[2] + bias, 0.f), fmaxf(a1[3] + bias, 0.f));
            const int cl = (wave * 4 + j) * 16 + lh;
            const int r0 = lg * 4;
            s_f1[(r0 + 0) * 264 + cl] = (ushort_t)p01;
            s_f1[(r0 + 1) * 264 + cl] = (ushort_t)(p01 >> 16);
            s_f1[(r0 + 2) * 264 + cl] = (ushort_t)p23;
            s_f1[(r0 + 3) * 264 + cl] = (ushort_t)(p23 >> 16);
            s_f1[(16 + r0 + 0) * 264 + cl] = (ushort_t)q01;
            s_f1[(16 + r0 + 1) * 264 + cl] = (ushort_t)(q01 >> 16);
            s_f1[(16 + r0 + 2) * 264 + cl] = (ushort_t)q23;
            s_f1[(16 + r0 + 3) * 264 + cl] = (ushort_t)(q23 >> 16);
        }
        __syncthreads();
        // ---- FFN2 partial: f1[32x256] @ w2[:, r*256:+256]^T, acc regs ----
#pragma unroll 2
        for (int kk = 0; kk < 8; kk++) {
            bf16x8 a0 = *(const bf16x8*)(s_f1 + lh * 264 + kk * 32 + lg * 8);
            bf16x8 a1 = *(const bf16x8*)(s_f1 + (16 + lh) * 264 + kk * 32 + lg * 8);
            bf16x8 b0 = *(const bf16x8*)(w2_bf + (size_t)col0 * 512 + r * 256 + kk * 32 + lg * 8);
            bf16x8 b1v = *(const bf16x8*)(w2_bf + (size_t)col1 * 512 + r * 256 + kk * 32 + lg * 8);
            f00 = MFMA(a0, b0, f00);  f01 = MFMA(a1, b0, f01);
            f10 = MFMA(a0, b1v, f10); f11 = MFMA(a1, b1v, f11);
        }
        __syncthreads();
    }
    // ---- f2 -> s_f2 (fp32, aliases s_f1; reads drained by barrier above) ----
    {
        const float bi0 = b2[col0], bi1 = b2[col1];
#pragma unroll
        for (int i = 0; i < 4; i++) {
            s_f2[(lg * 4 + i) * 132 + col0]      = f00[i] + bi0;
            s_f2[(16 + lg * 4 + i) * 132 + col0] = f01[i] + bi0;
            s_f2[(lg * 4 + i) * 132 + col1]      = f10[i] + bi1;
            s_f2[(16 + lg * 4 + i) * 132 + col1] = f11[i] + bi1;
        }
    }
    __syncthreads();

    // ================= LN2, out write, h2 -> s_h =============================
    float h2[16];
    {
        float t[16]; float sum = 0.f;
#pragma unroll
        for (int i = 0; i < 16; i++) { t[i] = h1[i] + s_f2[l * 132 + ds + i]; sum += t[i]; }
        sum += __shfl_xor(sum, 1); sum += __shfl_xor(sum, 2); sum += __shfl_xor(sum, 4);
        float mean = sum * (1.f / 128.f);
        float vs = 0.f;
#pragma unroll
        for (int i = 0; i < 16; i++) { float d = t[i] - mean; vs += d * d; }
        vs += __shfl_xor(vs, 1); vs += __shfl_xor(vs, 2); vs += __shfl_xor(vs, 4);
        float rs = rsqrtf(vs * (1.f / 128.f) + 1e-5f);
#pragma unroll
        for (int i = 0; i < 16; i++)
            h2[i] = (t[i] - mean) * rs * ln2g[ds + i] + ln2b[ds + i];
    }
    {
        float4* po = (float4*)(out_xt + (size_t)n * 4096 + tid * 16);
#pragma unroll
        for (int q = 0; q < 4; q++)
            po[q] = make_float4(h2[4 * q], h2[4 * q + 1], h2[4 * q + 2], h2[4 * q + 3]);
    }
    store16bf(s_h + l * 136 + ds, h2);
    __syncthreads();

    // ================= GCN weight GEMM: hh = h2 @ gcnw^T (bf16 out) ==========
    {
        bf16x8 af[2][4];
#pragma unroll
        for (int mt = 0; mt < 2; mt++)
#pragma unroll
            for (int kk = 0; kk < 4; kk++)
                af[mt][kk] = *(const bf16x8*)(s_h + (mt * 16 + lh) * 136 + kk * 32 + lg * 8);
#pragma unroll
        for (int j = 0; j < 2; j++) {
            const int nt = wave * 2 + j;
            f32x4 a0 = {0.f, 0.f, 0.f, 0.f}, a1 = {0.f, 0.f, 0.f, 0.f};
#pragma unroll
            for (int kk = 0; kk < 4; kk++) {
                bf16x8 b = *(const bf16x8*)(wg_bf + (size_t)(nt * 16 + lh) * 128 + kk * 32 + lg * 8);
                a0 = MFMA(af[0][kk], b, a0);
                a1 = MFMA(af[1][kk], b, a1);
            }
            const int col = nt * 16 + lh;
            ushort_t* hp = hh + (size_t)n * 4096;
            uint32 p01 = cvtpk(a0[0], a0[1]);
            uint32 p23 = cvtpk(a0[2], a0[3]);
            uint32 q01 = cvtpk(a1[0], a1[1]);
            uint32 q23 = cvtpk(a1[2], a1[3]);
            const int r0 = lg * 4;
            hp[(r0 + 0) * 128 + col] = (ushort_t)p01;
            hp[(r0 + 1) * 128 + col] = (ushort_t)(p01 >> 16);
            hp[(r0 + 2) * 128 + col] = (ushort_t)p23;
            hp[(r0 + 3) * 128 + col] = (ushort_t)(p23 >> 16);
            hp[(16 + r0 + 0) * 128 + col] = (ushort_t)q01;
            hp[(16 + r0 + 1) * 128 + col] = (ushort_t)(q01 >> 16);
            hp[(16 + r0 + 2) * 128 + col] = (ushort_t)q23;
            hp[(16 + r0 + 3) * 128 + col] = (ushort_t)(q23 >> 16);
        }
    }
}

// ---------------------------------------------------------------------------
// GCN support kernels (unchanged)
// ---------------------------------------------------------------------------
__global__ void k_init(float* deg, int* count) {
    int i = blockIdx.x * 256 + threadIdx.x;
    if (i < BDIM * KDIM) { deg[i] = 1.0f; count[i] = 0; }
}

__global__ void k_degcount(const int* __restrict__ ei, const float* __restrict__ ew,
                           float* deg, int* count) {
    int idx = blockIdx.x * 256 + threadIdx.x;
    if (idx >= BDIM * EDIM) return;
    int b = idx / EDIM, e = idx - b * EDIM;
    int col = ei[(size_t)b * 2 * EDIM + EDIM + e];
    float w = ew[(size_t)b * EDIM + e];
    atomicAdd(&deg[b * KDIM + col], w);
    atomicAdd(&count[b * KDIM + col], 1);
}

__global__ __launch_bounds__(1024)
void k_scan(const int* __restrict__ count, int* offs, int* cursor) {
    __shared__ int s[KDIM];
    int b = blockIdx.x, i = threadIdx.x;
    int c = count[b * KDIM + i];
    s[i] = c; __syncthreads();
#pragma unroll 1
    for (int off = 1; off < KDIM; off <<= 1) {
        int t = (i >= off) ? s[i - off] : 0;
        __syncthreads();
        s[i] += t;
        __syncthreads();
    }
    int excl = s[i] - c;
    offs[b * KDIM + i] = excl;
    cursor[b * KDIM + i] = excl;
}

__global__ void k_fill(const int* __restrict__ ei, int* cursor, int* elist) {
    int idx = blockIdx.x * 256 + threadIdx.x;
    if (idx >= BDIM * EDIM) return;
    int b = idx / EDIM, e = idx - b * EDIM;
    int col = ei[(size_t)b * 2 * EDIM + EDIM + e];
    int pos = atomicAdd(&cursor[b * KDIM + col], 1);
    elist[(size_t)b * EDIM + pos] = e;
}

__global__ __launch_bounds__(256)
void k_gather(const int* __restrict__ ei, const float* __restrict__ ew,
              const float* __restrict__ deg, const int* __restrict__ offs,
              const int* __restrict__ count, const int* __restrict__ elist,
              const ushort_t* __restrict__ hh, const float* __restrict__ gcn_b,
              float* __restrict__ out)
{
    const int node = blockIdx.x;
    const int b = node >> 10, i = node & 1023;
    const int tid = threadIdx.x;
    const float dcol = rsqrtf(deg[node]);
    const int off = offs[node], cnt = count[node];
    const ushort_t* hhb = hh + ((size_t)b * KDIM) * 4096;

    float acc[16];
    {
        const uint4* ph = (const uint4*)(hhb + (size_t)i * 4096 + tid * 16);
        uint4 a = ph[0], bb = ph[1];
        float tmp[16]; unpack8(a, tmp); unpack8(bb, tmp + 8);
        float nrm = dcol * dcol;
#pragma unroll
        for (int k = 0; k < 16; k++) acc[k] = tmp[k] * nrm;
    }
    for (int t = 0; t < cnt; t++) {
        int e = elist[(size_t)b * EDIM + off + t];
        int row = ei[(size_t)b * 2 * EDIM + e];
        float w = ew[(size_t)b * EDIM + e];
        float nrm = rsqrtf(deg[b * KDIM + row]) * w * dcol;
        const uint4* ph = (const uint4*)(hhb + (size_t)row * 4096 + tid * 16);
        uint4 a = ph[0], bb = ph[1];
        float tmp[16]; unpack8(a, tmp); unpack8(bb, tmp + 8);
#pragma unroll
        for (int k = 0; k < 16; k++) acc[k] += tmp[k] * nrm;
    }
    const int d0 = (tid * 16) & 127;
    float4* po = (float4*)(out + (size_t)node * 4096 + tid * 16);
#pragma unroll
    for (int q = 0; q < 4; q++) {
        float4 xo = po[q];
        xo.x += acc[4 * q]     + gcn_b[d0 + 4 * q];
        xo.y += acc[4 * q + 1] + gcn_b[d0 + 4 * q + 1];
        xo.z += acc[4 * q + 2] + gcn_b[d0 + 4 * q + 2];
        xo.w += acc[4 * q + 3] + gcn_b[d0 + 4 * q + 3];
        po[q] = xo;
    }
}

// ---------------------------------------------------------------------------
extern "C" void kernel_launch(void* const* d_in, const int* in_sizes, int n_in,
                              void* d_out, int out_size, void* d_ws, size_t ws_size,
                              hipStream_t stream) {
    const float* x     = (const float*)d_in[0];
    const int*   ei    = (const int*)d_in[1];
    const float* ew    = (const float*)d_in[2];
    const float* w_qkv = (const float*)d_in[3];
    const float* b_qkv = (const float*)d_in[4];
    const float* w_out = (const float*)d_in[5];
    const float* b_out = (const float*)d_in[6];
    const float* w1    = (const float*)d_in[7];
    const float* b1    = (const float*)d_in[8];
    const float* w2    = (const float*)d_in[9];
    const float* b2    = (const float*)d_in[10];
    const float* ln1g  = (const float*)d_in[11];
    const float* ln1b  = (const float*)d_in[12];
    const float* ln2g  = (const float*)d_in[13];
    const float* ln2b  = (const float*)d_in[14];
    const float* gcnw  = (const float*)d_in[15];
    const float* gcnb  = (const float*)d_in[16];
    float* out = (float*)d_out;

    // ws layout (bytes): weights 425984 | deg/count/offs/cursor 4x16384 | elist 262144 | hh 33554432
    char* ws = (char*)d_ws;
    ushort_t* wbf   = (ushort_t*)ws;
    ushort_t* wq_bf = wbf;
    ushort_t* wo_bf = wbf + 49152;
    ushort_t* w1_bf = wbf + 65536;
    ushort_t* w2_bf = wbf + 131072;
    ushort_t* wg_bf = wbf + 196608;
    float*    deg   = (float*)(ws + 425984);
    int*      count = (int*)(ws + 442368);
    int*      offs  = (int*)(ws + 458752);
    int*      cursor= (int*)(ws + 475136);
    int*      elist = (int*)(ws + 491520);
    ushort_t* hh    = (ushort_t*)(ws + 753664);

    k_prep<<<(NWCVT + 255) / 256, 256, 0, stream>>>(w_qkv, w_out, w1, w2, gcnw, wbf);
    k_init<<<16, 256, 0, stream>>>(deg, count);
    k_transformer<<<NSEQ, 256, 0, stream>>>(x, wq_bf, b_qkv, wo_bf, b_out,
                                            w1_bf, b1, w2_bf, b2, wg_bf,
                                            ln1g, ln1b, ln2g, ln2b, out, hh);
    k_degcount<<<256, 256, 0, stream>>>(ei, ew, deg, count);
    k_scan<<<BDIM, 1024, 0, stream>>>(count, offs, cursor);
    k_fill<<<256, 256, 0, stream>>>(ei, cursor, elist);
    k_gather<<<NSEQ, 256, 0, stream>>>(ei, ew, deg, offs, count, elist, hh, gcnb, out);
}

// Round 8
// 348.275 us; speedup vs baseline: 22.1154x; 1.0267x over previous
//
#include <hip/hip_runtime.h>
#include <hip/hip_bf16.h>

// Problem constants
#define BDIM 4
#define KDIM 1024
#define EDIM 16384
#define NSEQ (BDIM * KDIM)   // 4096

typedef unsigned short ushort_t;
typedef unsigned int   uint32;

typedef __bf16 bf16x8 __attribute__((ext_vector_type(8)));
typedef float  f32x4  __attribute__((ext_vector_type(4)));

#define MFMA(A, B, C) __builtin_amdgcn_mfma_f32_16x16x32_bf16((A), (B), (C), 0, 0, 0)

__device__ __forceinline__ float bf2f(uint32 u) {
    union { uint32 i; float f; } v; v.i = u << 16; return v.f;
}
__device__ __forceinline__ ushort_t f2bf(float f) {
    union { float f; uint32 i; } v; v.f = f;
    uint32 r = (v.i + 0x7fffu + ((v.i >> 16) & 1u)) >> 16;
    return (ushort_t)r;
}
// hardware packed cvt: {lo=bf16(a), hi=bf16(b)}, RNE
__device__ __forceinline__ uint32 cvtpk(float a, float b) {
    uint32 r;
    asm("v_cvt_pk_bf16_f32 %0, %1, %2" : "=v"(r) : "v"(a), "v"(b));
    return r;
}
__device__ __forceinline__ ushort_t f2bf_hw(float f) { return (ushort_t)cvtpk(f, f); }

__device__ __forceinline__ void unpack8(uint4 v, float* dst) {
    const uint32* pv = (const uint32*)&v;
#pragma unroll
    for (int q = 0; q < 4; q++) {
        uint32 w = pv[q];
        dst[2 * q]     = bf2f(w & 0xffffu);
        dst[2 * q + 1] = bf2f(w >> 16);
    }
}
// pack 16 floats -> 16 bf16 (32B) at p (16B-aligned)
__device__ __forceinline__ void store16bf(ushort_t* p, const float* v) {
    uint32 w[8];
#pragma unroll
    for (int q = 0; q < 8; q++) w[q] = cvtpk(v[2 * q], v[2 * q + 1]);
    ((uint4*)p)[0] = make_uint4(w[0], w[1], w[2], w[3]);
    ((uint4*)p)[1] = make_uint4(w[4], w[5], w[6], w[7]);
}

// ---------------------------------------------------------------------------
// Weight pre-conversion fp32 -> bf16 into ws:
//   wqkv [384][128] @0 | wout [128][128] @49152 | w1 [512][128] @65536
//   w2 [128][512] @131072 | gcnw [128][128] @196608   (elements)
// ---------------------------------------------------------------------------
#define NWCVT 212992
__global__ void k_prep(const float* __restrict__ wq, const float* __restrict__ wo,
                       const float* __restrict__ w1, const float* __restrict__ w2,
                       const float* __restrict__ wg, ushort_t* __restrict__ dst) {
    int i = blockIdx.x * 256 + threadIdx.x;
    if (i >= NWCVT) return;
    float v;
    if      (i <  49152) v = wq[i];
    else if (i <  65536) v = wo[i - 49152];
    else if (i < 131072) v = w1[i - 65536];
    else if (i < 196608) v = w2[i - 131072];
    else                 v = wg[i - 196608];
    dst[i] = f2bf(v);
}

// ---------------------------------------------------------------------------
// Fused transformer layer v6 = v2 (round-4 green) + weight prefetch ONLY.
// __launch_bounds__(256) exactly as v2 (no min-waves cap — bisect variable).
// LDS map (35840 B):
//   regionH @0     [32][136] bf16 (8704):  s_h (h0 bf16)  <-> s_o (attn out)
//   regionM @8704  (16896): s_qk [32][264] bf16 (Q|K) -> s_p -> s_u f32 [32][132]
//                           -> s_f1 [32][264] bf16 -> s_f2 f32 [32][132]
//   s_vt  @25600  [128][40] bf16 (10240): V transposed [dh_global][key]
// ---------------------------------------------------------------------------
__global__ __launch_bounds__(256)
void k_transformer(const float* __restrict__ x,
                   const ushort_t* __restrict__ wq_bf, const float* __restrict__ b_qkv,
                   const ushort_t* __restrict__ wo_bf, const float* __restrict__ b_out,
                   const ushort_t* __restrict__ w1_bf, const float* __restrict__ b1,
                   const ushort_t* __restrict__ w2_bf, const float* __restrict__ b2,
                   const ushort_t* __restrict__ wg_bf,
                   const float* __restrict__ ln1g, const float* __restrict__ ln1b,
                   const float* __restrict__ ln2g, const float* __restrict__ ln2b,
                   float* __restrict__ out_xt, ushort_t* __restrict__ hh)
{
    const int n    = blockIdx.x;
    const int tid  = threadIdx.x;
    const int wave = tid >> 6;
    const int lane = tid & 63;
    const int lh   = lane & 15;      // M-row / N-col within 16x16 tile
    const int lg   = lane >> 4;      // k-group (8 elems each)
    const int l    = tid >> 3;       // per-thread row (LN phases)
    const int ds   = (tid & 7) * 16;

    __shared__ __align__(16) char smem[35840];
    ushort_t* s_h  = (ushort_t*)(smem);            // aliases s_o
    ushort_t* s_o  = (ushort_t*)(smem);
    ushort_t* s_qk = (ushort_t*)(smem + 8704);     // aliases s_p/s_u/s_f1/s_f2
    ushort_t* s_p  = (ushort_t*)(smem + 8704);
    float*    s_u  = (float*)(smem + 8704);
    ushort_t* s_f1 = (ushort_t*)(smem + 8704);
    float*    s_f2 = (float*)(smem + 8704);
    ushort_t* s_vt = (ushort_t*)(smem + 25600);

    // ---- load h0 (fp32, thread owns row l cols ds..ds+16) + bf16 to s_h ----
    float h0[16];
    {
        const float4* px = (const float4*)(x + (size_t)n * 4096 + tid * 16);
#pragma unroll
        for (int q = 0; q < 4; q++) {
            float4 v = px[q];
            h0[4 * q] = v.x; h0[4 * q + 1] = v.y; h0[4 * q + 2] = v.z; h0[4 * q + 3] = v.w;
        }
    }
    store16bf(s_h + l * 136 + ds, h0);
    __syncthreads();

    // ================= QKV: [32x128] @ wqkv^T -> Q,K (s_qk) and V^T (s_vt) ==
    {
        bf16x8 af[2][4];
#pragma unroll
        for (int mt = 0; mt < 2; mt++)
#pragma unroll
            for (int kk = 0; kk < 4; kk++)
                af[mt][kk] = *(const bf16x8*)(s_h + (mt * 16 + lh) * 136 + kk * 32 + lg * 8);
        const int ntb = wave * 6;
        bf16x8 bw[2][4];
#pragma unroll
        for (int kk = 0; kk < 4; kk++)
            bw[0][kk] = *(const bf16x8*)(wq_bf + (size_t)(ntb * 16 + lh) * 128 + kk * 32 + lg * 8);
#pragma unroll
        for (int j = 0; j < 6; j++) {
            const int cur = j & 1, nxt = cur ^ 1;
            if (j < 5) {
#pragma unroll
                for (int kk = 0; kk < 4; kk++)
                    bw[nxt][kk] = *(const bf16x8*)(wq_bf + (size_t)((ntb + j + 1) * 16 + lh) * 128 + kk * 32 + lg * 8);
            }
            const int nt = ntb + j;
            f32x4 a0 = {0.f, 0.f, 0.f, 0.f}, a1 = {0.f, 0.f, 0.f, 0.f};
#pragma unroll
            for (int kk = 0; kk < 4; kk++) {
                a0 = MFMA(af[0][kk], bw[cur][kk], a0);
                a1 = MFMA(af[1][kk], bw[cur][kk], a1);
            }
            const int col = nt * 16 + lh;
            const float bias = b_qkv[col];
            uint32 p01 = cvtpk(a0[0] + bias, a0[1] + bias);
            uint32 p23 = cvtpk(a0[2] + bias, a0[3] + bias);
            uint32 q01 = cvtpk(a1[0] + bias, a1[1] + bias);
            uint32 q23 = cvtpk(a1[2] + bias, a1[3] + bias);
            if (nt < 16) {          // Q (cols 0-127) and K (cols 128-255)
                const int r0 = lg * 4;
                s_qk[(r0 + 0) * 264 + col] = (ushort_t)p01;
                s_qk[(r0 + 1) * 264 + col] = (ushort_t)(p01 >> 16);
                s_qk[(r0 + 2) * 264 + col] = (ushort_t)p23;
                s_qk[(r0 + 3) * 264 + col] = (ushort_t)(p23 >> 16);
                s_qk[(16 + r0 + 0) * 264 + col] = (ushort_t)q01;
                s_qk[(16 + r0 + 1) * 264 + col] = (ushort_t)(q01 >> 16);
                s_qk[(16 + r0 + 2) * 264 + col] = (ushort_t)q23;
                s_qk[(16 + r0 + 3) * 264 + col] = (ushort_t)(q23 >> 16);
            } else {                // V -> transposed s_vt[dh_global][key]
                const int vc = col - 256;
                *(uint32*)&s_vt[vc * 40 + lg * 4]          = p01;
                *(uint32*)&s_vt[vc * 40 + lg * 4 + 2]      = p23;
                *(uint32*)&s_vt[vc * 40 + 16 + lg * 4]     = q01;
                *(uint32*)&s_vt[vc * 40 + 16 + lg * 4 + 2] = q23;
            }
        }
    }
    __syncthreads();

    // ================= QK^T (K=16 via zero-padded K=32), per-wave 2 heads ====
    f32x4 sA[2][2][2];   // [head][mt][nt]
    {
        bf16x8 bz = {};
#pragma unroll
        for (int hd = 0; hd < 2; hd++) {
            const int h8 = wave * 2 + hd;
#pragma unroll
            for (int mt = 0; mt < 2; mt++) {
                bf16x8 aq = *(const bf16x8*)(s_qk + (mt * 16 + lh) * 264 + h8 * 16 + (lg & 1) * 8);
#pragma unroll
                for (int nt = 0; nt < 2; nt++) {
                    bf16x8 bk = bz;
                    if (lg < 2)
                        bk = *(const bf16x8*)(s_qk + (nt * 16 + lh) * 264 + 128 + h8 * 16 + lg * 8);
                    f32x4 z = {0.f, 0.f, 0.f, 0.f};
                    sA[hd][mt][nt] = MFMA(aq, bk, z);
                }
            }
        }
    }

    // ---- softmax in registers ----
    float pvf[2][16];
#pragma unroll
    for (int hd = 0; hd < 2; hd++) {
#pragma unroll
        for (int mt = 0; mt < 2; mt++) {
#pragma unroll
            for (int i = 0; i < 4; i++) {
                float v0 = sA[hd][mt][0][i] * 0.25f;   // 1/sqrt(dh=16)
                float v1 = sA[hd][mt][1][i] * 0.25f;
                float mx = fmaxf(v0, v1);
#pragma unroll
                for (int m = 1; m < 16; m <<= 1) mx = fmaxf(mx, __shfl_xor(mx, m));
                float e0 = __expf(v0 - mx), e1 = __expf(v1 - mx);
                float sm = e0 + e1;
#pragma unroll
                for (int m = 1; m < 16; m <<= 1) sm += __shfl_xor(sm, m);
                float inv = 1.0f / sm;
                pvf[hd][mt * 8 + i]     = e0 * inv;
                pvf[hd][mt * 8 + 4 + i] = e1 * inv;
            }
        }
    }
    __syncthreads();   // all QK^T reads of s_qk complete -> safe to write P
#pragma unroll
    for (int hd = 0; hd < 2; hd++) {
        const int h8 = wave * 2 + hd;
#pragma unroll
        for (int mt = 0; mt < 2; mt++)
#pragma unroll
            for (int nt = 0; nt < 2; nt++) {
                uint32 r01 = cvtpk(pvf[hd][mt * 8 + nt * 4 + 0], pvf[hd][mt * 8 + nt * 4 + 1]);
                uint32 r23 = cvtpk(pvf[hd][mt * 8 + nt * 4 + 2], pvf[hd][mt * 8 + nt * 4 + 3]);
                const int r0 = mt * 16 + lg * 4, c = h8 * 32 + nt * 16 + lh;
                s_p[(r0 + 0) * 264 + c] = (ushort_t)r01;
                s_p[(r0 + 1) * 264 + c] = (ushort_t)(r01 >> 16);
                s_p[(r0 + 2) * 264 + c] = (ushort_t)r23;
                s_p[(r0 + 3) * 264 + c] = (ushort_t)(r23 >> 16);
            }
    }
    __syncthreads();

    // ================= PV: P[32x32] @ V[32x16] per head -> s_o (@regionH) ====
#pragma unroll
    for (int hd = 0; hd < 2; hd++) {
        const int h8 = wave * 2 + hd;
        bf16x8 bv = *(const bf16x8*)(s_vt + (h8 * 16 + lh) * 40 + lg * 8);
#pragma unroll
        for (int mt = 0; mt < 2; mt++) {
            bf16x8 ap = *(const bf16x8*)(s_p + (mt * 16 + lh) * 264 + h8 * 32 + lg * 8);
            f32x4 z = {0.f, 0.f, 0.f, 0.f};
            f32x4 o = MFMA(ap, bv, z);
            uint32 r01 = cvtpk(o[0], o[1]);
            uint32 r23 = cvtpk(o[2], o[3]);
            const int r0 = mt * 16 + lg * 4, c = h8 * 16 + lh;
            s_o[(r0 + 0) * 136 + c] = (ushort_t)r01;
            s_o[(r0 + 1) * 136 + c] = (ushort_t)(r01 >> 16);
            s_o[(r0 + 2) * 136 + c] = (ushort_t)r23;
            s_o[(r0 + 3) * 136 + c] = (ushort_t)(r23 >> 16);
        }
    }
    __syncthreads();

    // ================= W_out: o[32x128] @ wout^T + b -> s_u (fp32) ===========
    {
        bf16x8 af[2][4];
#pragma unroll
        for (int mt = 0; mt < 2; mt++)
#pragma unroll
            for (int kk = 0; kk < 4; kk++)
                af[mt][kk] = *(const bf16x8*)(s_o + (mt * 16 + lh) * 136 + kk * 32 + lg * 8);
#pragma unroll
        for (int j = 0; j < 2; j++) {
            const int nt = wave * 2 + j;
            f32x4 a0 = {0.f, 0.f, 0.f, 0.f}, a1 = {0.f, 0.f, 0.f, 0.f};
#pragma unroll
            for (int kk = 0; kk < 4; kk++) {
                bf16x8 b = *(const bf16x8*)(wo_bf + (size_t)(nt * 16 + lh) * 128 + kk * 32 + lg * 8);
                a0 = MFMA(af[0][kk], b, a0);
                a1 = MFMA(af[1][kk], b, a1);
            }
            const int col = nt * 16 + lh;
            const float bias = b_out[col];
#pragma unroll
            for (int i = 0; i < 4; i++) {
                s_u[(lg * 4 + i) * 132 + col]      = a0[i] + bias;
                s_u[(16 + lg * 4 + i) * 132 + col] = a1[i] + bias;
            }
        }
    }
    __syncthreads();

    // ================= LN1 (per-thread row layout) ===========================
    float h1[16];
    {
        float t[16]; float sum = 0.f;
#pragma unroll
        for (int i = 0; i < 16; i++) { t[i] = h0[i] + s_u[l * 132 + ds + i]; sum += t[i]; }
        sum += __shfl_xor(sum, 1); sum += __shfl_xor(sum, 2); sum += __shfl_xor(sum, 4);
        float mean = sum * (1.f / 128.f);
        float vs = 0.f;
#pragma unroll
        for (int i = 0; i < 16; i++) { float d = t[i] - mean; vs += d * d; }
        vs += __shfl_xor(vs, 1); vs += __shfl_xor(vs, 2); vs += __shfl_xor(vs, 4);
        float rs = rsqrtf(vs * (1.f / 128.f) + 1e-5f);
#pragma unroll
        for (int i = 0; i < 16; i++)
            h1[i] = (t[i] - mean) * rs * ln1g[ds + i] + ln1b[ds + i];
    }
    store16bf(s_h + l * 136 + ds, h1);   // overwrites s_o (reads done)
    __syncthreads();

    // ================= FFN (two K=256 rounds, acc in regs) ===================
    f32x4 f00 = {0.f,0.f,0.f,0.f}, f01 = {0.f,0.f,0.f,0.f};
    f32x4 f10 = {0.f,0.f,0.f,0.f}, f11 = {0.f,0.f,0.f,0.f};
    const int col0 = wave * 32 + lh, col1 = col0 + 16;
    bf16x8 ah[2][4];
#pragma unroll
    for (int mt = 0; mt < 2; mt++)
#pragma unroll
        for (int kk = 0; kk < 4; kk++)
            ah[mt][kk] = *(const bf16x8*)(s_h + (mt * 16 + lh) * 136 + kk * 32 + lg * 8);

#pragma unroll
    for (int r = 0; r < 2; r++) {
        // ---- FFN1 quarter: 4 column-tiles per wave -> s_f1 [32][264] ----
        bf16x8 bw[2][4];
        {
            const int nt0 = (r * 16 + wave * 4) * 16 + lh;
#pragma unroll
            for (int kk = 0; kk < 4; kk++)
                bw[0][kk] = *(const bf16x8*)(w1_bf + (size_t)nt0 * 128 + kk * 32 + lg * 8);
        }
#pragma unroll
        for (int j = 0; j < 4; j++) {
            const int cur = j & 1, nxt = cur ^ 1;
            if (j < 3) {
                const int ntn = (r * 16 + wave * 4 + j + 1) * 16 + lh;
#pragma unroll
                for (int kk = 0; kk < 4; kk++)
                    bw[nxt][kk] = *(const bf16x8*)(w1_bf + (size_t)ntn * 128 + kk * 32 + lg * 8);
            }
            f32x4 a0 = {0.f,0.f,0.f,0.f}, a1 = {0.f,0.f,0.f,0.f};
#pragma unroll
            for (int kk = 0; kk < 4; kk++) {
                a0 = MFMA(ah[0][kk], bw[cur][kk], a0);
                a1 = MFMA(ah[1][kk], bw[cur][kk], a1);
            }
            const float bias = b1[(r * 16 + wave * 4 + j) * 16 + lh];
            uint32 p01 = cvtpk(fmaxf(a0[0] + bias, 0.f), fmaxf(a0[1] + bias, 0.f));
            uint32 p23 = cvtpk(fmaxf(a0[2] + bias, 0.f), fmaxf(a0[3] + bias, 0.f));
            uint32 q01 = cvtpk(fmaxf(a1[0] + bias, 0.f), fmaxf(a1[1] + bias, 0.f));
            uint32 q23 = cvtpk(fmaxf(a1[2] + bias, 0.f), fmaxf(a1[3] + bias, 0.f));
            const int cl = (wave * 4 + j) * 16 + lh;
            const int r0 = lg * 4;
            s_f1[(r0 + 0) * 264 + cl] = (ushort_t)p01;
            s_f1[(r0 + 1) * 264 + cl] = (ushort_t)(p01 >> 16);
            s_f1[(r0 + 2) * 264 + cl] = (ushort_t)p23;
            s_f1[(r0 + 3) * 264 + cl] = (ushort_t)(p23 >> 16);
            s_f1[(16 + r0 + 0) * 264 + cl] = (ushort_t)q01;
            s_f1[(16 + r0 + 1) * 264 + cl] = (ushort_t)(q01 >> 16);
            s_f1[(16 + r0 + 2) * 264 + cl] = (ushort_t)q23;
            s_f1[(16 + r0 + 3) * 264 + cl] = (ushort_t)(q23 >> 16);
        }
        __syncthreads();
        // ---- FFN2 partial: f1[32x256] @ w2-slice, acc in regs ----
        bf16x8 wp[2][2];
        wp[0][0] = *(const bf16x8*)(w2_bf + (size_t)col0 * 512 + r * 256 + lg * 8);
        wp[0][1] = *(const bf16x8*)(w2_bf + (size_t)col1 * 512 + r * 256 + lg * 8);
#pragma unroll
        for (int kk = 0; kk < 8; kk++) {
            const int cur = kk & 1, nxt = cur ^ 1;
            if (kk < 7) {
                wp[nxt][0] = *(const bf16x8*)(w2_bf + (size_t)col0 * 512 + r * 256 + (kk + 1) * 32 + lg * 8);
                wp[nxt][1] = *(const bf16x8*)(w2_bf + (size_t)col1 * 512 + r * 256 + (kk + 1) * 32 + lg * 8);
            }
            bf16x8 a0 = *(const bf16x8*)(s_f1 + lh * 264 + kk * 32 + lg * 8);
            bf16x8 a1 = *(const bf16x8*)(s_f1 + (16 + lh) * 264 + kk * 32 + lg * 8);
            f00 = MFMA(a0, wp[cur][0], f00);  f01 = MFMA(a1, wp[cur][0], f01);
            f10 = MFMA(a0, wp[cur][1], f10);  f11 = MFMA(a1, wp[cur][1], f11);
        }
        __syncthreads();
    }
    // ---- f2 -> s_f2 (fp32, aliases s_f1; reads drained by barrier above) ----
    {
        const float bi0 = b2[col0], bi1 = b2[col1];
#pragma unroll
        for (int i = 0; i < 4; i++) {
            s_f2[(lg * 4 + i) * 132 + col0]      = f00[i] + bi0;
            s_f2[(16 + lg * 4 + i) * 132 + col0] = f01[i] + bi0;
            s_f2[(lg * 4 + i) * 132 + col1]      = f10[i] + bi1;
            s_f2[(16 + lg * 4 + i) * 132 + col1] = f11[i] + bi1;
        }
    }
    __syncthreads();

    // ================= LN2, out write, h2 -> s_h =============================
    float h2[16];
    {
        float t[16]; float sum = 0.f;
#pragma unroll
        for (int i = 0; i < 16; i++) { t[i] = h1[i] + s_f2[l * 132 + ds + i]; sum += t[i]; }
        sum += __shfl_xor(sum, 1); sum += __shfl_xor(sum, 2); sum += __shfl_xor(sum, 4);
        float mean = sum * (1.f / 128.f);
        float vs = 0.f;
#pragma unroll
        for (int i = 0; i < 16; i++) { float d = t[i] - mean; vs += d * d; }
        vs += __shfl_xor(vs, 1); vs += __shfl_xor(vs, 2); vs += __shfl_xor(vs, 4);
        float rs = rsqrtf(vs * (1.f / 128.f) + 1e-5f);
#pragma unroll
        for (int i = 0; i < 16; i++)
            h2[i] = (t[i] - mean) * rs * ln2g[ds + i] + ln2b[ds + i];
    }
    {
        float4* po = (float4*)(out_xt + (size_t)n * 4096 + tid * 16);
#pragma unroll
        for (int q = 0; q < 4; q++)
            po[q] = make_float4(h2[4 * q], h2[4 * q + 1], h2[4 * q + 2], h2[4 * q + 3]);
    }
    store16bf(s_h + l * 136 + ds, h2);
    __syncthreads();

    // ================= GCN weight GEMM: hh = h2 @ gcnw^T (bf16 out) ==========
    {
        bf16x8 af[2][4];
#pragma unroll
        for (int mt = 0; mt < 2; mt++)
#pragma unroll
            for (int kk = 0; kk < 4; kk++)
                af[mt][kk] = *(const bf16x8*)(s_h + (mt * 16 + lh) * 136 + kk * 32 + lg * 8);
#pragma unroll
        for (int j = 0; j < 2; j++) {
            const int nt = wave * 2 + j;
            f32x4 a0 = {0.f, 0.f, 0.f, 0.f}, a1 = {0.f, 0.f, 0.f, 0.f};
#pragma unroll
            for (int kk = 0; kk < 4; kk++) {
                bf16x8 b = *(const bf16x8*)(wg_bf + (size_t)(nt * 16 + lh) * 128 + kk * 32 + lg * 8);
                a0 = MFMA(af[0][kk], b, a0);
                a1 = MFMA(af[1][kk], b, a1);
            }
            const int col = nt * 16 + lh;
            ushort_t* hp = hh + (size_t)n * 4096;
            uint32 p01 = cvtpk(a0[0], a0[1]);
            uint32 p23 = cvtpk(a0[2], a0[3]);
            uint32 q01 = cvtpk(a1[0], a1[1]);
            uint32 q23 = cvtpk(a1[2], a1[3]);
            const int r0 = lg * 4;
            hp[(r0 + 0) * 128 + col] = (ushort_t)p01;
            hp[(r0 + 1) * 128 + col] = (ushort_t)(p01 >> 16);
            hp[(r0 + 2) * 128 + col] = (ushort_t)p23;
            hp[(r0 + 3) * 128 + col] = (ushort_t)(p23 >> 16);
            hp[(16 + r0 + 0) * 128 + col] = (ushort_t)q01;
            hp[(16 + r0 + 1) * 128 + col] = (ushort_t)(q01 >> 16);
            hp[(16 + r0 + 2) * 128 + col] = (ushort_t)q23;
            hp[(16 + r0 + 3) * 128 + col] = (ushort_t)(q23 >> 16);
        }
    }
}

// ---------------------------------------------------------------------------
// GCN support kernels (unchanged)
// ---------------------------------------------------------------------------
__global__ void k_init(float* deg, int* count) {
    int i = blockIdx.x * 256 + threadIdx.x;
    if (i < BDIM * KDIM) { deg[i] = 1.0f; count[i] = 0; }
}

__global__ void k_degcount(const int* __restrict__ ei, const float* __restrict__ ew,
                           float* deg, int* count) {
    int idx = blockIdx.x * 256 + threadIdx.x;
    if (idx >= BDIM * EDIM) return;
    int b = idx / EDIM, e = idx - b * EDIM;
    int col = ei[(size_t)b * 2 * EDIM + EDIM + e];
    float w = ew[(size_t)b * EDIM + e];
    atomicAdd(&deg[b * KDIM + col], w);
    atomicAdd(&count[b * KDIM + col], 1);
}

__global__ __launch_bounds__(1024)
void k_scan(const int* __restrict__ count, int* offs, int* cursor) {
    __shared__ int s[KDIM];
    int b = blockIdx.x, i = threadIdx.x;
    int c = count[b * KDIM + i];
    s[i] = c; __syncthreads();
#pragma unroll 1
    for (int off = 1; off < KDIM; off <<= 1) {
        int t = (i >= off) ? s[i - off] : 0;
        __syncthreads();
        s[i] += t;
        __syncthreads();
    }
    int excl = s[i] - c;
    offs[b * KDIM + i] = excl;
    cursor[b * KDIM + i] = excl;
}

__global__ void k_fill(const int* __restrict__ ei, int* cursor, int* elist) {
    int idx = blockIdx.x * 256 + threadIdx.x;
    if (idx >= BDIM * EDIM) return;
    int b = idx / EDIM, e = idx - b * EDIM;
    int col = ei[(size_t)b * 2 * EDIM + EDIM + e];
    int pos = atomicAdd(&cursor[b * KDIM + col], 1);
    elist[(size_t)b * EDIM + pos] = e;
}

__global__ __launch_bounds__(256)
void k_gather(const int* __restrict__ ei, const float* __restrict__ ew,
              const float* __restrict__ deg, const int* __restrict__ offs,
              const int* __restrict__ count, const int* __restrict__ elist,
              const ushort_t* __restrict__ hh, const float* __restrict__ gcn_b,
              float* __restrict__ out)
{
    const int node = blockIdx.x;
    const int b = node >> 10, i = node & 1023;
    const int tid = threadIdx.x;
    const float dcol = rsqrtf(deg[node]);
    const int off = offs[node], cnt = count[node];
    const ushort_t* hhb = hh + ((size_t)b * KDIM) * 4096;

    float acc[16];
    {
        const uint4* ph = (const uint4*)(hhb + (size_t)i * 4096 + tid * 16);
        uint4 a = ph[0], bb = ph[1];
        float tmp[16]; unpack8(a, tmp); unpack8(bb, tmp + 8);
        float nrm = dcol * dcol;
#pragma unroll
        for (int k = 0; k < 16; k++) acc[k] = tmp[k] * nrm;
    }
    for (int t = 0; t < cnt; t++) {
        int e = elist[(size_t)b * EDIM + off + t];
        int row = ei[(size_t)b * 2 * EDIM + e];
        float w = ew[(size_t)b * EDIM + e];
        float nrm = rsqrtf(deg[b * KDIM + row]) * w * dcol;
        const uint4* ph = (const uint4*)(hhb + (size_t)row * 4096 + tid * 16);
        uint4 a = ph[0], bb = ph[1];
        float tmp[16]; unpack8(a, tmp); unpack8(bb, tmp + 8);
#pragma unroll
        for (int k = 0; k < 16; k++) acc[k] += tmp[k] * nrm;
    }
    const int d0 = (tid * 16) & 127;
    float4* po = (float4*)(out + (size_t)node * 4096 + tid * 16);
#pragma unroll
    for (int q = 0; q < 4; q++) {
        float4 xo = po[q];
        xo.x += acc[4 * q]     + gcn_b[d0 + 4 * q];
        xo.y += acc[4 * q + 1] + gcn_b[d0 + 4 * q + 1];
        xo.z += acc[4 * q + 2] + gcn_b[d0 + 4 * q + 2];
        xo.w += acc[4 * q + 3] + gcn_b[d0 + 4 * q + 3];
        po[q] = xo;
    }
}

// ---------------------------------------------------------------------------
extern "C" void kernel_launch(void* const* d_in, const int* in_sizes, int n_in,
                              void* d_out, int out_size, void* d_ws, size_t ws_size,
                              hipStream_t stream) {
    const float* x     = (const float*)d_in[0];
    const int*   ei    = (const int*)d_in[1];
    const float* ew    = (const float*)d_in[2];
    const float* w_qkv = (const float*)d_in[3];
    const float* b_qkv = (const float*)d_in[4];
    const float* w_out = (const float*)d_in[5];
    const float* b_out = (const float*)d_in[6];
    const float* w1    = (const float*)d_in[7];
    const float* b1    = (const float*)d_in[8];
    const float* w2    = (const float*)d_in[9];
    const float* b2    = (const float*)d_in[10];
    const float* ln1g  = (const float*)d_in[11];
    const float* ln1b  = (const float*)d_in[12];
    const float* ln2g  = (const float*)d_in[13];
    const float* ln2b  = (const float*)d_in[14];
    const float* gcnw  = (const float*)d_in[15];
    const float* gcnb  = (const float*)d_in[16];
    float* out = (float*)d_out;

    // ws layout (bytes): weights 425984 | deg/count/offs/cursor 4x16384 | elist 262144 | hh 33554432
    char* ws = (char*)d_ws;
    ushort_t* wbf   = (ushort_t*)ws;
    ushort_t* wq_bf = wbf;
    ushort_t* wo_bf = wbf + 49152;
    ushort_t* w1_bf = wbf + 65536;
    ushort_t* w2_bf = wbf + 131072;
    ushort_t* wg_bf = wbf + 196608;
    float*    deg   = (float*)(ws + 425984);
    int*      count = (int*)(ws + 442368);
    int*      offs  = (int*)(ws + 458752);
    int*      cursor= (int*)(ws + 475136);
    int*      elist = (int*)(ws + 491520);
    ushort_t* hh    = (ushort_t*)(ws + 753664);

    k_prep<<<(NWCVT + 255) / 256, 256, 0, stream>>>(w_qkv, w_out, w1, w2, gcnw, wbf);
    k_init<<<16, 256, 0, stream>>>(deg, count);
    k_transformer<<<NSEQ, 256, 0, stream>>>(x, wq_bf, b_qkv, wo_bf, b_out,
                                            w1_bf, b1, w2_bf, b2, wg_bf,
                                            ln1g, ln1b, ln2g, ln2b, out, hh);
    k_degcount<<<256, 256, 0, stream>>>(ei, ew, deg, count);
    k_scan<<<BDIM, 1024, 0, stream>>>(count, offs, cursor);
    k_fill<<<256, 256, 0, stream>>>(ei, cursor, elist);
    k_gather<<<NSEQ, 256, 0, stream>>>(ei, ew, deg, offs, count, elist, hh, gcnb, out);
}

// Round 9
// 333.824 us; speedup vs baseline: 23.0727x; 1.0433x over previous
//
#include <hip/hip_runtime.h>
#include <hip/hip_bf16.h>

// Problem constants
#define BDIM 4
#define KDIM 1024
#define EDIM 16384
#define NSEQ (BDIM * KDIM)   // 4096

typedef unsigned short ushort_t;
typedef unsigned int   uint32;

typedef __bf16 bf16x8 __attribute__((ext_vector_type(8)));
typedef float  f32x4  __attribute__((ext_vector_type(4)));

#define MFMA(A, B, C) __builtin_amdgcn_mfma_f32_16x16x32_bf16((A), (B), (C), 0, 0, 0)

__device__ __forceinline__ float bf2f(uint32 u) {
    union { uint32 i; float f; } v; v.i = u << 16; return v.f;
}
__device__ __forceinline__ ushort_t f2bf(float f) {
    union { float f; uint32 i; } v; v.f = f;
    uint32 r = (v.i + 0x7fffu + ((v.i >> 16) & 1u)) >> 16;
    return (ushort_t)r;
}
// hardware packed cvt: {lo=bf16(a), hi=bf16(b)}, RNE
__device__ __forceinline__ uint32 cvtpk(float a, float b) {
    uint32 r;
    asm("v_cvt_pk_bf16_f32 %0, %1, %2" : "=v"(r) : "v"(a), "v"(b));
    return r;
}
__device__ __forceinline__ ushort_t f2bf_hw(float f) { return (ushort_t)cvtpk(f, f); }

__device__ __forceinline__ void unpack8(uint4 v, float* dst) {
    const uint32* pv = (const uint32*)&v;
#pragma unroll
    for (int q = 0; q < 4; q++) {
        uint32 w = pv[q];
        dst[2 * q]     = bf2f(w & 0xffffu);
        dst[2 * q + 1] = bf2f(w >> 16);
    }
}
// pack 16 floats -> 16 bf16 (32B) at p (16B-aligned)
__device__ __forceinline__ void store16bf(ushort_t* p, const float* v) {
    uint32 w[8];
#pragma unroll
    for (int q = 0; q < 8; q++) w[q] = cvtpk(v[2 * q], v[2 * q + 1]);
    ((uint4*)p)[0] = make_uint4(w[0], w[1], w[2], w[3]);
    ((uint4*)p)[1] = make_uint4(w[4], w[5], w[6], w[7]);
}

// ---------------------------------------------------------------------------
// Weight pre-conversion fp32 -> bf16 into ws:
//   wqkv [384][128] @0 | wout [128][128] @49152 | w1 [512][128] @65536
//   w2 [128][512] @131072 | gcnw [128][128] @196608   (elements)
// ---------------------------------------------------------------------------
#define NWCVT 212992
__global__ void k_prep(const float* __restrict__ wq, const float* __restrict__ wo,
                       const float* __restrict__ w1, const float* __restrict__ w2,
                       const float* __restrict__ wg, ushort_t* __restrict__ dst) {
    int i = blockIdx.x * 256 + threadIdx.x;
    if (i >= NWCVT) return;
    float v;
    if      (i <  49152) v = wq[i];
    else if (i <  65536) v = wo[i - 49152];
    else if (i < 131072) v = w1[i - 65536];
    else if (i < 196608) v = w2[i - 131072];
    else                 v = wg[i - 196608];
    dst[i] = f2bf(v);
}

// ---------------------------------------------------------------------------
// Fused transformer layer v7 = v6 (green, 262us) + distance-2 weight prefetch
// + bias/ln preloads + early weight-load issue. NO launch_bounds min-waves
// (the (256,4) cap miscompiles/spills — pinned by r7/r8 bisect).
// LDS map (35840 B, 4 blocks/CU):
//   regionH @0     [32][136] bf16 (8704):  s_h (h0 bf16)  <-> s_o (attn out)
//   regionM @8704  (16896): s_qk [32][264] bf16 (Q|K) -> s_p -> s_u f32 [32][132]
//                           -> s_f1 [32][264] bf16 -> s_f2 f32 [32][132]
//   s_vt  @25600  [128][40] bf16 (10240): V transposed [dh_global][key]
// ---------------------------------------------------------------------------
__global__ __launch_bounds__(256)
void k_transformer(const float* __restrict__ x,
                   const ushort_t* __restrict__ wq_bf, const float* __restrict__ b_qkv,
                   const ushort_t* __restrict__ wo_bf, const float* __restrict__ b_out,
                   const ushort_t* __restrict__ w1_bf, const float* __restrict__ b1,
                   const ushort_t* __restrict__ w2_bf, const float* __restrict__ b2,
                   const ushort_t* __restrict__ wg_bf,
                   const float* __restrict__ ln1g, const float* __restrict__ ln1b,
                   const float* __restrict__ ln2g, const float* __restrict__ ln2b,
                   float* __restrict__ out_xt, ushort_t* __restrict__ hh)
{
    const int n    = blockIdx.x;
    const int tid  = threadIdx.x;
    const int wave = tid >> 6;
    const int lane = tid & 63;
    const int lh   = lane & 15;      // M-row / N-col within 16x16 tile
    const int lg   = lane >> 4;      // k-group (8 elems each)
    const int l    = tid >> 3;       // per-thread row (LN phases)
    const int ds   = (tid & 7) * 16;

    __shared__ __align__(16) char smem[35840];
    ushort_t* s_h  = (ushort_t*)(smem);            // aliases s_o
    ushort_t* s_o  = (ushort_t*)(smem);
    ushort_t* s_qk = (ushort_t*)(smem + 8704);     // aliases s_p/s_u/s_f1/s_f2
    ushort_t* s_p  = (ushort_t*)(smem + 8704);
    float*    s_u  = (float*)(smem + 8704);
    ushort_t* s_f1 = (ushort_t*)(smem + 8704);
    float*    s_f2 = (float*)(smem + 8704);
    ushort_t* s_vt = (ushort_t*)(smem + 25600);

    // ---- load h0 (fp32, thread owns row l cols ds..ds+16) + bf16 to s_h ----
    float h0[16];
    {
        const float4* px = (const float4*)(x + (size_t)n * 4096 + tid * 16);
#pragma unroll
        for (int q = 0; q < 4; q++) {
            float4 v = px[q];
            h0[4 * q] = v.x; h0[4 * q + 1] = v.y; h0[4 * q + 2] = v.z; h0[4 * q + 3] = v.w;
        }
    }
    store16bf(s_h + l * 136 + ds, h0);
    __syncthreads();

    // ================= QKV: [32x128] @ wqkv^T -> Q,K (s_qk) and V^T (s_vt) ==
    {
        const int ntb = wave * 6;
        // preload biases for my 6 column-tiles
        float biasv[6];
#pragma unroll
        for (int j = 0; j < 6; j++) biasv[j] = b_qkv[(ntb + j) * 16 + lh];
        // distance-2, 3-buffer weight prefetch
        bf16x8 bw[3][4];
#pragma unroll
        for (int kk = 0; kk < 4; kk++)
            bw[0][kk] = *(const bf16x8*)(wq_bf + (size_t)(ntb * 16 + lh) * 128 + kk * 32 + lg * 8);
#pragma unroll
        for (int kk = 0; kk < 4; kk++)
            bw[1][kk] = *(const bf16x8*)(wq_bf + (size_t)((ntb + 1) * 16 + lh) * 128 + kk * 32 + lg * 8);
        bf16x8 af[2][4];
#pragma unroll
        for (int mt = 0; mt < 2; mt++)
#pragma unroll
            for (int kk = 0; kk < 4; kk++)
                af[mt][kk] = *(const bf16x8*)(s_h + (mt * 16 + lh) * 136 + kk * 32 + lg * 8);
#pragma unroll
        for (int j = 0; j < 6; j++) {
            const int cur = j % 3, pf = (j + 2) % 3;
            if (j < 4) {
#pragma unroll
                for (int kk = 0; kk < 4; kk++)
                    bw[pf][kk] = *(const bf16x8*)(wq_bf + (size_t)((ntb + j + 2) * 16 + lh) * 128 + kk * 32 + lg * 8);
            }
            const int nt = ntb + j;
            f32x4 a0 = {0.f, 0.f, 0.f, 0.f}, a1 = {0.f, 0.f, 0.f, 0.f};
#pragma unroll
            for (int kk = 0; kk < 4; kk++) {
                a0 = MFMA(af[0][kk], bw[cur][kk], a0);
                a1 = MFMA(af[1][kk], bw[cur][kk], a1);
            }
            const int col = nt * 16 + lh;
            const float bias = biasv[j];
            uint32 p01 = cvtpk(a0[0] + bias, a0[1] + bias);
            uint32 p23 = cvtpk(a0[2] + bias, a0[3] + bias);
            uint32 q01 = cvtpk(a1[0] + bias, a1[1] + bias);
            uint32 q23 = cvtpk(a1[2] + bias, a1[3] + bias);
            if (nt < 16) {          // Q (cols 0-127) and K (cols 128-255)
                const int r0 = lg * 4;
                s_qk[(r0 + 0) * 264 + col] = (ushort_t)p01;
                s_qk[(r0 + 1) * 264 + col] = (ushort_t)(p01 >> 16);
                s_qk[(r0 + 2) * 264 + col] = (ushort_t)p23;
                s_qk[(r0 + 3) * 264 + col] = (ushort_t)(p23 >> 16);
                s_qk[(16 + r0 + 0) * 264 + col] = (ushort_t)q01;
                s_qk[(16 + r0 + 1) * 264 + col] = (ushort_t)(q01 >> 16);
                s_qk[(16 + r0 + 2) * 264 + col] = (ushort_t)q23;
                s_qk[(16 + r0 + 3) * 264 + col] = (ushort_t)(q23 >> 16);
            } else {                // V -> transposed s_vt[dh_global][key]
                const int vc = col - 256;
                *(uint32*)&s_vt[vc * 40 + lg * 4]          = p01;
                *(uint32*)&s_vt[vc * 40 + lg * 4 + 2]      = p23;
                *(uint32*)&s_vt[vc * 40 + 16 + lg * 4]     = q01;
                *(uint32*)&s_vt[vc * 40 + 16 + lg * 4 + 2] = q23;
            }
        }
    }
    __syncthreads();

    // ================= QK^T (K=16 via zero-padded K=32), per-wave 2 heads ====
    f32x4 sA[2][2][2];   // [head][mt][nt]
    {
        bf16x8 bz = {};
#pragma unroll
        for (int hd = 0; hd < 2; hd++) {
            const int h8 = wave * 2 + hd;
#pragma unroll
            for (int mt = 0; mt < 2; mt++) {
                bf16x8 aq = *(const bf16x8*)(s_qk + (mt * 16 + lh) * 264 + h8 * 16 + (lg & 1) * 8);
#pragma unroll
                for (int nt = 0; nt < 2; nt++) {
                    bf16x8 bk = bz;
                    if (lg < 2)
                        bk = *(const bf16x8*)(s_qk + (nt * 16 + lh) * 264 + 128 + h8 * 16 + lg * 8);
                    f32x4 z = {0.f, 0.f, 0.f, 0.f};
                    sA[hd][mt][nt] = MFMA(aq, bk, z);
                }
            }
        }
    }

    // ---- softmax in registers ----
    float pvf[2][16];
#pragma unroll
    for (int hd = 0; hd < 2; hd++) {
#pragma unroll
        for (int mt = 0; mt < 2; mt++) {
#pragma unroll
            for (int i = 0; i < 4; i++) {
                float v0 = sA[hd][mt][0][i] * 0.25f;   // 1/sqrt(dh=16)
                float v1 = sA[hd][mt][1][i] * 0.25f;
                float mx = fmaxf(v0, v1);
#pragma unroll
                for (int m = 1; m < 16; m <<= 1) mx = fmaxf(mx, __shfl_xor(mx, m));
                float e0 = __expf(v0 - mx), e1 = __expf(v1 - mx);
                float sm = e0 + e1;
#pragma unroll
                for (int m = 1; m < 16; m <<= 1) sm += __shfl_xor(sm, m);
                float inv = 1.0f / sm;
                pvf[hd][mt * 8 + i]     = e0 * inv;
                pvf[hd][mt * 8 + 4 + i] = e1 * inv;
            }
        }
    }
    __syncthreads();   // all QK^T reads of s_qk complete -> safe to write P
#pragma unroll
    for (int hd = 0; hd < 2; hd++) {
        const int h8 = wave * 2 + hd;
#pragma unroll
        for (int mt = 0; mt < 2; mt++)
#pragma unroll
            for (int nt = 0; nt < 2; nt++) {
                uint32 r01 = cvtpk(pvf[hd][mt * 8 + nt * 4 + 0], pvf[hd][mt * 8 + nt * 4 + 1]);
                uint32 r23 = cvtpk(pvf[hd][mt * 8 + nt * 4 + 2], pvf[hd][mt * 8 + nt * 4 + 3]);
                const int r0 = mt * 16 + lg * 4, c = h8 * 32 + nt * 16 + lh;
                s_p[(r0 + 0) * 264 + c] = (ushort_t)r01;
                s_p[(r0 + 1) * 264 + c] = (ushort_t)(r01 >> 16);
                s_p[(r0 + 2) * 264 + c] = (ushort_t)r23;
                s_p[(r0 + 3) * 264 + c] = (ushort_t)(r23 >> 16);
            }
    }
    __syncthreads();

    // ================= PV: P[32x32] @ V[32x16] per head -> s_o (@regionH) ====
    // Issue W_out weight loads EARLY so their latency hides under PV.
    bf16x8 wbo[2][4];
#pragma unroll
    for (int j = 0; j < 2; j++)
#pragma unroll
        for (int kk = 0; kk < 4; kk++)
            wbo[j][kk] = *(const bf16x8*)(wo_bf + (size_t)((wave * 2 + j) * 16 + lh) * 128 + kk * 32 + lg * 8);
    float bo0 = b_out[(wave * 2 + 0) * 16 + lh];
    float bo1 = b_out[(wave * 2 + 1) * 16 + lh];
#pragma unroll
    for (int hd = 0; hd < 2; hd++) {
        const int h8 = wave * 2 + hd;
        bf16x8 bv = *(const bf16x8*)(s_vt + (h8 * 16 + lh) * 40 + lg * 8);
#pragma unroll
        for (int mt = 0; mt < 2; mt++) {
            bf16x8 ap = *(const bf16x8*)(s_p + (mt * 16 + lh) * 264 + h8 * 32 + lg * 8);
            f32x4 z = {0.f, 0.f, 0.f, 0.f};
            f32x4 o = MFMA(ap, bv, z);
            uint32 r01 = cvtpk(o[0], o[1]);
            uint32 r23 = cvtpk(o[2], o[3]);
            const int r0 = mt * 16 + lg * 4, c = h8 * 16 + lh;
            s_o[(r0 + 0) * 136 + c] = (ushort_t)r01;
            s_o[(r0 + 1) * 136 + c] = (ushort_t)(r01 >> 16);
            s_o[(r0 + 2) * 136 + c] = (ushort_t)r23;
            s_o[(r0 + 3) * 136 + c] = (ushort_t)(r23 >> 16);
        }
    }
    __syncthreads();

    // ================= W_out: o[32x128] @ wout^T + b -> s_u (fp32) ===========
    {
        bf16x8 af[2][4];
#pragma unroll
        for (int mt = 0; mt < 2; mt++)
#pragma unroll
            for (int kk = 0; kk < 4; kk++)
                af[mt][kk] = *(const bf16x8*)(s_o + (mt * 16 + lh) * 136 + kk * 32 + lg * 8);
#pragma unroll
        for (int j = 0; j < 2; j++) {
            f32x4 a0 = {0.f, 0.f, 0.f, 0.f}, a1 = {0.f, 0.f, 0.f, 0.f};
#pragma unroll
            for (int kk = 0; kk < 4; kk++) {
                a0 = MFMA(af[0][kk], wbo[j][kk], a0);
                a1 = MFMA(af[1][kk], wbo[j][kk], a1);
            }
            const int col = (wave * 2 + j) * 16 + lh;
            const float bias = j ? bo1 : bo0;
#pragma unroll
            for (int i = 0; i < 4; i++) {
                s_u[(lg * 4 + i) * 132 + col]      = a0[i] + bias;
                s_u[(16 + lg * 4 + i) * 132 + col] = a1[i] + bias;
            }
        }
    }
    __syncthreads();

    // ================= LN1 (per-thread row layout) ===========================
    float h1[16];
    {
        float g[16], be[16];
        {
            const float4* pg = (const float4*)(ln1g + ds);
            const float4* pb = (const float4*)(ln1b + ds);
#pragma unroll
            for (int q = 0; q < 4; q++) {
                float4 vg = pg[q], vb = pb[q];
                g[4*q]=vg.x; g[4*q+1]=vg.y; g[4*q+2]=vg.z; g[4*q+3]=vg.w;
                be[4*q]=vb.x; be[4*q+1]=vb.y; be[4*q+2]=vb.z; be[4*q+3]=vb.w;
            }
        }
        float t[16]; float sum = 0.f;
#pragma unroll
        for (int i = 0; i < 16; i++) { t[i] = h0[i] + s_u[l * 132 + ds + i]; sum += t[i]; }
        sum += __shfl_xor(sum, 1); sum += __shfl_xor(sum, 2); sum += __shfl_xor(sum, 4);
        float mean = sum * (1.f / 128.f);
        float vs = 0.f;
#pragma unroll
        for (int i = 0; i < 16; i++) { float d = t[i] - mean; vs += d * d; }
        vs += __shfl_xor(vs, 1); vs += __shfl_xor(vs, 2); vs += __shfl_xor(vs, 4);
        float rs = rsqrtf(vs * (1.f / 128.f) + 1e-5f);
#pragma unroll
        for (int i = 0; i < 16; i++)
            h1[i] = (t[i] - mean) * rs * g[i] + be[i];
    }
    store16bf(s_h + l * 136 + ds, h1);   // overwrites s_o (reads done)
    __syncthreads();

    // ================= FFN (two K=256 rounds, acc in regs) ===================
    f32x4 f00 = {0.f,0.f,0.f,0.f}, f01 = {0.f,0.f,0.f,0.f};
    f32x4 f10 = {0.f,0.f,0.f,0.f}, f11 = {0.f,0.f,0.f,0.f};
    const int col0 = wave * 32 + lh, col1 = col0 + 16;
    bf16x8 ah[2][4];
#pragma unroll
    for (int mt = 0; mt < 2; mt++)
#pragma unroll
        for (int kk = 0; kk < 4; kk++)
            ah[mt][kk] = *(const bf16x8*)(s_h + (mt * 16 + lh) * 136 + kk * 32 + lg * 8);

#pragma unroll
    for (int r = 0; r < 2; r++) {
        // ---- FFN1 quarter: 4 column-tiles per wave -> s_f1 [32][264] ----
        float b1v[4];
#pragma unroll
        for (int j = 0; j < 4; j++) b1v[j] = b1[(r * 16 + wave * 4 + j) * 16 + lh];
        bf16x8 bw[3][4];
#pragma unroll
        for (int kk = 0; kk < 4; kk++)
            bw[0][kk] = *(const bf16x8*)(w1_bf + (size_t)((r * 16 + wave * 4) * 16 + lh) * 128 + kk * 32 + lg * 8);
#pragma unroll
        for (int kk = 0; kk < 4; kk++)
            bw[1][kk] = *(const bf16x8*)(w1_bf + (size_t)((r * 16 + wave * 4 + 1) * 16 + lh) * 128 + kk * 32 + lg * 8);
#pragma unroll
        for (int j = 0; j < 4; j++) {
            const int cur = j % 3, pf = (j + 2) % 3;
            if (j < 2) {
                const int ntn = (r * 16 + wave * 4 + j + 2) * 16 + lh;
#pragma unroll
                for (int kk = 0; kk < 4; kk++)
                    bw[pf][kk] = *(const bf16x8*)(w1_bf + (size_t)ntn * 128 + kk * 32 + lg * 8);
            }
            f32x4 a0 = {0.f,0.f,0.f,0.f}, a1 = {0.f,0.f,0.f,0.f};
#pragma unroll
            for (int kk = 0; kk < 4; kk++) {
                a0 = MFMA(ah[0][kk], bw[cur][kk], a0);
                a1 = MFMA(ah[1][kk], bw[cur][kk], a1);
            }
            const float bias = b1v[j];
            uint32 p01 = cvtpk(fmaxf(a0[0] + bias, 0.f), fmaxf(a0[1] + bias, 0.f));
            uint32 p23 = cvtpk(fmaxf(a0[2] + bias, 0.f), fmaxf(a0[3] + bias, 0.f));
            uint32 q01 = cvtpk(fmaxf(a1[0] + bias, 0.f), fmaxf(a1[1] + bias, 0.f));
            uint32 q23 = cvtpk(fmaxf(a1[2] + bias, 0.f), fmaxf(a1[3] + bias, 0.f));
            const int cl = (wave * 4 + j) * 16 + lh;
            const int r0 = lg * 4;
            s_f1[(r0 + 0) * 264 + cl] = (ushort_t)p01;
            s_f1[(r0 + 1) * 264 + cl] = (ushort_t)(p01 >> 16);
            s_f1[(r0 + 2) * 264 + cl] = (ushort_t)p23;
            s_f1[(r0 + 3) * 264 + cl] = (ushort_t)(p23 >> 16);
            s_f1[(16 + r0 + 0) * 264 + cl] = (ushort_t)q01;
            s_f1[(16 + r0 + 1) * 264 + cl] = (ushort_t)(q01 >> 16);
            s_f1[(16 + r0 + 2) * 264 + cl] = (ushort_t)q23;
            s_f1[(16 + r0 + 3) * 264 + cl] = (ushort_t)(q23 >> 16);
        }
        __syncthreads();
        // ---- FFN2 partial: f1[32x256] @ w2-slice, distance-2 prefetch ----
        bf16x8 wp[3][2];
        wp[0][0] = *(const bf16x8*)(w2_bf + (size_t)col0 * 512 + r * 256 + lg * 8);
        wp[0][1] = *(const bf16x8*)(w2_bf + (size_t)col1 * 512 + r * 256 + lg * 8);
        wp[1][0] = *(const bf16x8*)(w2_bf + (size_t)col0 * 512 + r * 256 + 32 + lg * 8);
        wp[1][1] = *(const bf16x8*)(w2_bf + (size_t)col1 * 512 + r * 256 + 32 + lg * 8);
#pragma unroll
        for (int kk = 0; kk < 8; kk++) {
            const int cur = kk % 3, pf = (kk + 2) % 3;
            if (kk < 6) {
                wp[pf][0] = *(const bf16x8*)(w2_bf + (size_t)col0 * 512 + r * 256 + (kk + 2) * 32 + lg * 8);
                wp[pf][1] = *(const bf16x8*)(w2_bf + (size_t)col1 * 512 + r * 256 + (kk + 2) * 32 + lg * 8);
            }
            bf16x8 a0 = *(const bf16x8*)(s_f1 + lh * 264 + kk * 32 + lg * 8);
            bf16x8 a1 = *(const bf16x8*)(s_f1 + (16 + lh) * 264 + kk * 32 + lg * 8);
            f00 = MFMA(a0, wp[cur][0], f00);  f01 = MFMA(a1, wp[cur][0], f01);
            f10 = MFMA(a0, wp[cur][1], f10);  f11 = MFMA(a1, wp[cur][1], f11);
        }
        __syncthreads();
    }
    // ---- f2 -> s_f2 (fp32, aliases s_f1; reads drained by barrier above) ----
    {
        const float bi0 = b2[col0], bi1 = b2[col1];
#pragma unroll
        for (int i = 0; i < 4; i++) {
            s_f2[(lg * 4 + i) * 132 + col0]      = f00[i] + bi0;
            s_f2[(16 + lg * 4 + i) * 132 + col0] = f01[i] + bi0;
            s_f2[(lg * 4 + i) * 132 + col1]      = f10[i] + bi1;
            s_f2[(16 + lg * 4 + i) * 132 + col1] = f11[i] + bi1;
        }
    }
    __syncthreads();

    // ================= LN2, out write, h2 -> s_h =============================
    // Issue GCN weight loads EARLY (consumed after next barrier).
    bf16x8 wbg[2][4];
#pragma unroll
    for (int j = 0; j < 2; j++)
#pragma unroll
        for (int kk = 0; kk < 4; kk++)
            wbg[j][kk] = *(const bf16x8*)(wg_bf + (size_t)((wave * 2 + j) * 16 + lh) * 128 + kk * 32 + lg * 8);
    float h2[16];
    {
        float g[16], be[16];
        {
            const float4* pg = (const float4*)(ln2g + ds);
            const float4* pb = (const float4*)(ln2b + ds);
#pragma unroll
            for (int q = 0; q < 4; q++) {
                float4 vg = pg[q], vb = pb[q];
                g[4*q]=vg.x; g[4*q+1]=vg.y; g[4*q+2]=vg.z; g[4*q+3]=vg.w;
                be[4*q]=vb.x; be[4*q+1]=vb.y; be[4*q+2]=vb.z; be[4*q+3]=vb.w;
            }
        }
        float t[16]; float sum = 0.f;
#pragma unroll
        for (int i = 0; i < 16; i++) { t[i] = h1[i] + s_f2[l * 132 + ds + i]; sum += t[i]; }
        sum += __shfl_xor(sum, 1); sum += __shfl_xor(sum, 2); sum += __shfl_xor(sum, 4);
        float mean = sum * (1.f / 128.f);
        float vs = 0.f;
#pragma unroll
        for (int i = 0; i < 16; i++) { float d = t[i] - mean; vs += d * d; }
        vs += __shfl_xor(vs, 1); vs += __shfl_xor(vs, 2); vs += __shfl_xor(vs, 4);
        float rs = rsqrtf(vs * (1.f / 128.f) + 1e-5f);
#pragma unroll
        for (int i = 0; i < 16; i++)
            h2[i] = (t[i] - mean) * rs * g[i] + be[i];
    }
    {
        float4* po = (float4*)(out_xt + (size_t)n * 4096 + tid * 16);
#pragma unroll
        for (int q = 0; q < 4; q++)
            po[q] = make_float4(h2[4 * q], h2[4 * q + 1], h2[4 * q + 2], h2[4 * q + 3]);
    }
    store16bf(s_h + l * 136 + ds, h2);
    __syncthreads();

    // ================= GCN weight GEMM: hh = h2 @ gcnw^T (bf16 out) ==========
    {
        bf16x8 af[2][4];
#pragma unroll
        for (int mt = 0; mt < 2; mt++)
#pragma unroll
            for (int kk = 0; kk < 4; kk++)
                af[mt][kk] = *(const bf16x8*)(s_h + (mt * 16 + lh) * 136 + kk * 32 + lg * 8);
#pragma unroll
        for (int j = 0; j < 2; j++) {
            f32x4 a0 = {0.f, 0.f, 0.f, 0.f}, a1 = {0.f, 0.f, 0.f, 0.f};
#pragma unroll
            for (int kk = 0; kk < 4; kk++) {
                a0 = MFMA(af[0][kk], wbg[j][kk], a0);
                a1 = MFMA(af[1][kk], wbg[j][kk], a1);
            }
            const int col = (wave * 2 + j) * 16 + lh;
            ushort_t* hp = hh + (size_t)n * 4096;
            uint32 p01 = cvtpk(a0[0], a0[1]);
            uint32 p23 = cvtpk(a0[2], a0[3]);
            uint32 q01 = cvtpk(a1[0], a1[1]);
            uint32 q23 = cvtpk(a1[2], a1[3]);
            const int r0 = lg * 4;
            hp[(r0 + 0) * 128 + col] = (ushort_t)p01;
            hp[(r0 + 1) * 128 + col] = (ushort_t)(p01 >> 16);
            hp[(r0 + 2) * 128 + col] = (ushort_t)p23;
            hp[(r0 + 3) * 128 + col] = (ushort_t)(p23 >> 16);
            hp[(16 + r0 + 0) * 128 + col] = (ushort_t)q01;
            hp[(16 + r0 + 1) * 128 + col] = (ushort_t)(q01 >> 16);
            hp[(16 + r0 + 2) * 128 + col] = (ushort_t)q23;
            hp[(16 + r0 + 3) * 128 + col] = (ushort_t)(q23 >> 16);
        }
    }
}

// ---------------------------------------------------------------------------
// GCN support kernels (unchanged)
// ---------------------------------------------------------------------------
__global__ void k_init(float* deg, int* count) {
    int i = blockIdx.x * 256 + threadIdx.x;
    if (i < BDIM * KDIM) { deg[i] = 1.0f; count[i] = 0; }
}

__global__ void k_degcount(const int* __restrict__ ei, const float* __restrict__ ew,
                           float* deg, int* count) {
    int idx = blockIdx.x * 256 + threadIdx.x;
    if (idx >= BDIM * EDIM) return;
    int b = idx / EDIM, e = idx - b * EDIM;
    int col = ei[(size_t)b * 2 * EDIM + EDIM + e];
    float w = ew[(size_t)b * EDIM + e];
    atomicAdd(&deg[b * KDIM + col], w);
    atomicAdd(&count[b * KDIM + col], 1);
}

__global__ __launch_bounds__(1024)
void k_scan(const int* __restrict__ count, int* offs, int* cursor) {
    __shared__ int s[KDIM];
    int b = blockIdx.x, i = threadIdx.x;
    int c = count[b * KDIM + i];
    s[i] = c; __syncthreads();
#pragma unroll 1
    for (int off = 1; off < KDIM; off <<= 1) {
        int t = (i >= off) ? s[i - off] : 0;
        __syncthreads();
        s[i] += t;
        __syncthreads();
    }
    int excl = s[i] - c;
    offs[b * KDIM + i] = excl;
    cursor[b * KDIM + i] = excl;
}

__global__ void k_fill(const int* __restrict__ ei, int* cursor, int* elist) {
    int idx = blockIdx.x * 256 + threadIdx.x;
    if (idx >= BDIM * EDIM) return;
    int b = idx / EDIM, e = idx - b * EDIM;
    int col = ei[(size_t)b * 2 * EDIM + EDIM + e];
    int pos = atomicAdd(&cursor[b * KDIM + col], 1);
    elist[(size_t)b * EDIM + pos] = e;
}

__global__ __launch_bounds__(256)
void k_gather(const int* __restrict__ ei, const float* __restrict__ ew,
              const float* __restrict__ deg, const int* __restrict__ offs,
              const int* __restrict__ count, const int* __restrict__ elist,
              const ushort_t* __restrict__ hh, const float* __restrict__ gcn_b,
              float* __restrict__ out)
{
    const int node = blockIdx.x;
    const int b = node >> 10, i = node & 1023;
    const int tid = threadIdx.x;
    const float dcol = rsqrtf(deg[node]);
    const int off = offs[node], cnt = count[node];
    const ushort_t* hhb = hh + ((size_t)b * KDIM) * 4096;

    float acc[16];
    {
        const uint4* ph = (const uint4*)(hhb + (size_t)i * 4096 + tid * 16);
        uint4 a = ph[0], bb = ph[1];
        float tmp[16]; unpack8(a, tmp); unpack8(bb, tmp + 8);
        float nrm = dcol * dcol;
#pragma unroll
        for (int k = 0; k < 16; k++) acc[k] = tmp[k] * nrm;
    }
    for (int t = 0; t < cnt; t++) {
        int e = elist[(size_t)b * EDIM + off + t];
        int row = ei[(size_t)b * 2 * EDIM + e];
        float w = ew[(size_t)b * EDIM + e];
        float nrm = rsqrtf(deg[b * KDIM + row]) * w * dcol;
        const uint4* ph = (const uint4*)(hhb + (size_t)row * 4096 + tid * 16);
        uint4 a = ph[0], bb = ph[1];
        float tmp[16]; unpack8(a, tmp); unpack8(bb, tmp + 8);
#pragma unroll
        for (int k = 0; k < 16; k++) acc[k] += tmp[k] * nrm;
    }
    const int d0 = (tid * 16) & 127;
    float4* po = (float4*)(out + (size_t)node * 4096 + tid * 16);
#pragma unroll
    for (int q = 0; q < 4; q++) {
        float4 xo = po[q];
        xo.x += acc[4 * q]     + gcn_b[d0 + 4 * q];
        xo.y += acc[4 * q + 1] + gcn_b[d0 + 4 * q + 1];
        xo.z += acc[4 * q + 2] + gcn_b[d0 + 4 * q + 2];
        xo.w += acc[4 * q + 3] + gcn_b[d0 + 4 * q + 3];
        po[q] = xo;
    }
}

// ---------------------------------------------------------------------------
extern "C" void kernel_launch(void* const* d_in, const int* in_sizes, int n_in,
                              void* d_out, int out_size, void* d_ws, size_t ws_size,
                              hipStream_t stream) {
    const float* x     = (const float*)d_in[0];
    const int*   ei    = (const int*)d_in[1];
    const float* ew    = (const float*)d_in[2];
    const float* w_qkv = (const float*)d_in[3];
    const float* b_qkv = (const float*)d_in[4];
    const float* w_out = (const float*)d_in[5];
    const float* b_out = (const float*)d_in[6];
    const float* w1    = (const float*)d_in[7];
    const float* b1    = (const float*)d_in[8];
    const float* w2    = (const float*)d_in[9];
    const float* b2    = (const float*)d_in[10];
    const float* ln1g  = (const float*)d_in[11];
    const float* ln1b  = (const float*)d_in[12];
    const float* ln2g  = (const float*)d_in[13];
    const float* ln2b  = (const float*)d_in[14];
    const float* gcnw  = (const float*)d_in[15];
    const float* gcnb  = (const float*)d_in[16];
    float* out = (float*)d_out;

    // ws layout (bytes): weights 425984 | deg/count/offs/cursor 4x16384 | elist 262144 | hh 33554432
    char* ws = (char*)d_ws;
    ushort_t* wbf   = (ushort_t*)ws;
    ushort_t* wq_bf = wbf;
    ushort_t* wo_bf = wbf + 49152;
    ushort_t* w1_bf = wbf + 65536;
    ushort_t* w2_bf = wbf + 131072;
    ushort_t* wg_bf = wbf + 196608;
    float*    deg   = (float*)(ws + 425984);
    int*      count = (int*)(ws + 442368);
    int*      offs  = (int*)(ws + 458752);
    int*      cursor= (int*)(ws + 475136);
    int*      elist = (int*)(ws + 491520);
    ushort_t* hh    = (ushort_t*)(ws + 753664);

    k_prep<<<(NWCVT + 255) / 256, 256, 0, stream>>>(w_qkv, w_out, w1, w2, gcnw, wbf);
    k_init<<<16, 256, 0, stream>>>(deg, count);
    k_transformer<<<NSEQ, 256, 0, stream>>>(x, wq_bf, b_qkv, wo_bf, b_out,
                                            w1_bf, b1, w2_bf, b2, wg_bf,
                                            ln1g, ln1b, ln2g, ln2b, out, hh);
    k_degcount<<<256, 256, 0, stream>>>(ei, ew, deg, count);
    k_scan<<<BDIM, 1024, 0, stream>>>(count, offs, cursor);
    k_fill<<<256, 256, 0, stream>>>(ei, cursor, elist);
    k_gather<<<NSEQ, 256, 0, stream>>>(ei, ew, deg, offs, count, elist, hh, gcnb, out);
}